// Round 3
// baseline (3119.833 us; speedup 1.0000x reference)
//
#include <hip/hip_runtime.h>

// ---------------------------------------------------------------------------
// EncoderDecoder (bi-LSTM encoder + attention decoder + CE loss), MI355X.
// Design: decouple the decoder LSTM recurrence (sequential, 50 steps) from the
// attention/logits heads (batched over all 50 steps as large bf16 MFMA GEMMs).
// All matmuls: bf16 MFMA 16x16x32, fp32 accumulate. ws usage ~167 MB
// (partial-LSE buffer aliases the encoder pre-activation buffers).
// ---------------------------------------------------------------------------

#define DI __device__ __forceinline__

typedef __attribute__((ext_vector_type(8))) short bf16x8; // 8 bf16 (4 VGPRs)
typedef __attribute__((ext_vector_type(4))) float f32x4;

DI float bf2f(short u) {
    union { float f; unsigned u; } c; c.u = ((unsigned)(unsigned short)u) << 16; return c.f;
}
DI short f2bf(float f) {
    union { float f; unsigned u; } c; c.f = f;
    unsigned r = c.u + 0x7fffu + ((c.u >> 16) & 1u);
    return (short)(r >> 16);
}
DI float sigm(float x) { return 1.f / (1.f + __expf(-x)); }
// overflow-free tanh: never inf/inf -> NaN
DI float tanh_(float x) {
    float e = __expf(-2.f * fabsf(x));
    float r = (1.f - e) / (1.f + e);
    return copysignf(r, x);
}

// ---------------------------------------------------------------------------
// Generic GEMM: C[m][n] = sum_k A[m][k]*B[n][k]  (both row-major, K contig)
// A: M x K bf16, B: N x K bf16. Block = 256 thr (4 waves). Block tile:
// (MT*16) rows x 64 cols; wave w owns cols [w*16, w*16+16).
// EPI 0: fp32 C + bias.  EPI 1: bf16 C = tanh(v+bias).  EPI 4: bf16 C = v+bias.
// EPI 3: fused LSE: v+=bias(out_b); grab target logit; partial sumexp per
//        (row, blockIdx.y*4+wave) -> partial[row*2000 + ...].
// ---------------------------------------------------------------------------
template<int MT, int EPI>
__global__ __launch_bounds__(256) void gemm_bt(
    const short* __restrict__ A, int lda,
    const short* __restrict__ B, int ldb,
    int K,
    const float* __restrict__ bias,
    void* __restrict__ Cout, int ldc,
    float* __restrict__ partial, const int* __restrict__ tgtf,
    float* __restrict__ tgtlog)
{
    const int lane = threadIdx.x & 63;
    const int wave = threadIdx.x >> 6;
    const int mbase = blockIdx.x * (MT * 16);
    const int ncol = blockIdx.y * 64 + wave * 16 + (lane & 15);
    const short* ap = A + (size_t)(mbase + (lane & 15)) * lda + ((lane >> 4) * 8);
    const short* bp = B + (size_t)ncol * ldb + ((lane >> 4) * 8);
    f32x4 acc[MT];
#pragma unroll
    for (int i = 0; i < MT; ++i) acc[i] = (f32x4){0.f, 0.f, 0.f, 0.f};
    for (int k = 0; k < K; k += 32) {
        bf16x8 bfr = *(const bf16x8*)(bp + k);
#pragma unroll
        for (int mt = 0; mt < MT; ++mt) {
            bf16x8 afr = *(const bf16x8*)(ap + (size_t)mt * 16 * lda + k);
            acc[mt] = __builtin_amdgcn_mfma_f32_16x16x32_bf16(afr, bfr, acc[mt], 0, 0, 0);
        }
    }
    const float bv = bias ? bias[ncol] : 0.f;
#pragma unroll
    for (int mt = 0; mt < MT; ++mt) {
#pragma unroll
        for (int r = 0; r < 4; ++r) {
            // verified C/D layout: col = lane&15, row = (lane>>4)*4 + r
            int row = mbase + mt * 16 + (lane >> 4) * 4 + r;
            float v = acc[mt][r] + bv;
            if constexpr (EPI == 0) {
                ((float*)Cout)[(size_t)row * ldc + ncol] = v;
            } else if constexpr (EPI == 1) {
                ((short*)Cout)[(size_t)row * ldc + ncol] = f2bf(tanh_(v));
            } else if constexpr (EPI == 4) {
                ((short*)Cout)[(size_t)row * ldc + ncol] = f2bf(v);
            } else if constexpr (EPI == 3) {
                if (ncol == tgtf[row]) tgtlog[row] = v;
                float e = __expf(v);
                e += __shfl_xor(e, 1); e += __shfl_xor(e, 2);
                e += __shfl_xor(e, 4); e += __shfl_xor(e, 8);
                if ((lane & 15) == 0)
                    partial[(size_t)row * 2000 + blockIdx.y * 4 + wave] = e;
            }
        }
    }
}

// ---------------------------------------------------------------------------
// One LSTM step: g = pre[t] + h_prev @ Whh_perm^T, gates, state update.
// Weights are gate-interleaved by row (perm n -> orig (n&3)*512 + (n>>2)) so
// a 64-col block owns all 4 gates of 16 h-indices -> single-kernel step.
// Grid: (32, ndir). M=64, N=2048, K=512.
// ---------------------------------------------------------------------------
struct StepArgs {
    const short* A;      // h_prev bf16 64x512
    const short* B;      // Whh perm bf16 2048x512
    const short* pre;    // pre-activations bf16, 64 rows x 2048 (bias folded)
    const float* cprev;  // 64x512
    float* cnext;        // 64x512
    short* h1; int ldh1; // bf16 h out (recurrent feed)
    short* h2; int ldh2; // optional second bf16 h out (cat right half)
    float* hs;           // optional fp32 h out (encoder hs), ld 512
};

__global__ __launch_bounds__(256) void lstm_step(StepArgs s0, StepArgs s1)
{
    StepArgs S = (blockIdx.y == 0) ? s0 : s1;
    const int lane = threadIdx.x & 63;
    const int wave = threadIdx.x >> 6;
    const int nb = blockIdx.x;
    const int lc = wave * 16 + (lane & 15);
    const int ncol = nb * 64 + lc;
    const short* ap = S.A + (lane & 15) * 512 + ((lane >> 4) * 8);
    const short* bp = S.B + (size_t)ncol * 512 + ((lane >> 4) * 8);
    f32x4 acc[4];
#pragma unroll
    for (int i = 0; i < 4; ++i) acc[i] = (f32x4){0.f, 0.f, 0.f, 0.f};
    for (int k = 0; k < 512; k += 32) {
        bf16x8 bfr = *(const bf16x8*)(bp + k);
#pragma unroll
        for (int mt = 0; mt < 4; ++mt) {
            bf16x8 afr = *(const bf16x8*)(ap + mt * 16 * 512 + k);
            acc[mt] = __builtin_amdgcn_mfma_f32_16x16x32_bf16(afr, bfr, acc[mt], 0, 0, 0);
        }
    }
    __shared__ float g[64 * 65]; // +1 pad: avoids bank conflict (16.6 KB)
#pragma unroll
    for (int mt = 0; mt < 4; ++mt)
#pragma unroll
        for (int r = 0; r < 4; ++r) {
            int row = mt * 16 + (lane >> 4) * 4 + r; // batch index
            g[row * 65 + lc] = acc[mt][r] + bf2f(S.pre[row * 2048 + ncol]);
        }
    __syncthreads();
#pragma unroll
    for (int it = 0; it < 4; ++it) {
        int item = threadIdx.x + it * 256; // 1024 items = 64 b x 16 jj
        int b = item >> 4, jj = item & 15;
        int j = nb * 16 + jj;
        float gi = g[b * 65 + jj * 4 + 0];
        float gf = g[b * 65 + jj * 4 + 1];
        float gg = g[b * 65 + jj * 4 + 2];
        float go = g[b * 65 + jj * 4 + 3];
        float cp = S.cprev[b * 512 + j];
        float cn = sigm(gf) * cp + sigm(gi) * tanh_(gg);
        float h  = sigm(go) * tanh_(cn);
        S.cnext[b * 512 + j] = cn;
        S.h1[b * S.ldh1 + j] = f2bf(h);
        if (S.h2) S.h2[b * S.ldh2 + j] = f2bf(h);
        if (S.hs) S.hs[b * 512 + j] = h;
    }
}

// ---------------------------------------------------------------------------
// prep: weight conversion/permutation to bf16, embedding gathers, bias sums,
// target-flat indices, zero-init of recurrent state and d_out.
// ---------------------------------------------------------------------------
struct PrepArgs {
    const float *Wih_f, *Whh_f, *Wih_b, *Whh_b, *Wih_d, *Whh_d;
    short *oWih_f, *oWhh_f, *oWih_b, *oWhh_b, *oWih_d, *oWhh_d;
    const float *Ws, *Wh, *lin, *outw;
    short *oWs, *oWh, *olin, *oout;
    const float *emb_src, *emb_tgt;
    const int *source, *target;
    short *A_src, *A_tgt;
    const float *bihf, *bhhf, *bihb, *bhhb, *bihd, *bhhd;
    float *bsumf, *bsumb, *bsumd;
    int *tgtf;
    short *hbfF0, *hbfB0;
    float *cF0, *cB0;
    float *dout;
};

__global__ __launch_bounds__(256) void prep_kernel(PrepArgs P)
{
    const long long total = 6LL * 1048576 + 262144 + 262144 + 524288 + 16384000
                          + 2097152 + 1638400 + 6144 + 3200 + 65536 + 65536 + 1;
    for (long long i = (long long)blockIdx.x * 256 + threadIdx.x; i < total;
         i += (long long)gridDim.x * 256) {
        long long t = i;
        if (t < 6LL * 1048576) { // gate-interleaved weight permute + bf16
            int seg = (int)(t >> 20); int r = (int)(t & 1048575);
            int n = r >> 9, k = r & 511;
            int orig = (n & 3) * 512 + (n >> 2);
            const float* s; short* d;
            switch (seg) {
                case 0: s = P.Wih_f; d = P.oWih_f; break;
                case 1: s = P.Whh_f; d = P.oWhh_f; break;
                case 2: s = P.Wih_b; d = P.oWih_b; break;
                case 3: s = P.Whh_b; d = P.oWhh_b; break;
                case 4: s = P.Wih_d; d = P.oWih_d; break;
                default: s = P.Whh_d; d = P.oWhh_d; break;
            }
            d[n * 512 + k] = f2bf(s[orig * 512 + k]);
            continue;
        }
        t -= 6LL * 1048576;
        if (t < 262144) { P.oWs[t] = f2bf(P.Ws[t]); continue; } t -= 262144;
        if (t < 262144) { P.oWh[t] = f2bf(P.Wh[t]); continue; } t -= 262144;
        if (t < 524288) { P.olin[t] = f2bf(P.lin[t]); continue; } t -= 524288;
        if (t < 16384000) { P.oout[t] = f2bf(P.outw[t]); continue; } t -= 16384000;
        if (t < 2097152) { // A_src row r = tt*64+b = xt[tt][b], PAD row -> 0
            int r = (int)(t >> 9), k = (int)(t & 511);
            int tt = r >> 6, b = r & 63;
            int tok = P.source[b * 64 + tt];
            P.A_src[t] = tok ? f2bf(P.emb_src[(size_t)tok * 512 + k]) : (short)0;
            continue;
        } t -= 2097152;
        if (t < 1638400) { // A_tgt row r = s*64+b = emb_tgt[target[b][s]], s=0..49
            int r = (int)(t >> 9), k = (int)(t & 511);
            int tt = r >> 6, b = r & 63;
            int tok = P.target[b * 51 + tt];
            P.A_tgt[t] = tok ? f2bf(P.emb_tgt[(size_t)tok * 512 + k]) : (short)0;
            continue;
        } t -= 1638400;
        if (t < 6144) { // bsum[net][n] = bih[orig] + bhh[orig] (permuted)
            int net = (int)(t >> 11); int n = (int)(t & 2047);
            int orig = (n & 3) * 512 + (n >> 2);
            if (net == 0)      P.bsumf[n] = P.bihf[orig] + P.bhhf[orig];
            else if (net == 1) P.bsumb[n] = P.bihb[orig] + P.bhhb[orig];
            else               P.bsumd[n] = P.bihd[orig] + P.bhhd[orig];
            continue;
        } t -= 6144;
        if (t < 3200) { // wt for step s = target[b][s+1]
            int s = (int)t >> 6, b = (int)t & 63;
            P.tgtf[t] = P.target[b * 51 + s + 1];
            continue;
        } t -= 3200;
        if (t < 65536) {
            if (t < 32768) P.hbfF0[t] = 0; else P.hbfB0[t - 32768] = 0;
            continue;
        } t -= 65536;
        if (t < 65536) {
            if (t < 32768) P.cF0[t] = 0.f; else P.cB0[t - 32768] = 0.f;
            continue;
        } t -= 65536;
        P.dout[0] = 0.f;
    }
}

// ---------------------------------------------------------------------------
// mid: enc_out = hs_f + hs_b (fp32 + bf16, layout (b,t,d)); hx0/c0 for decoder
// ---------------------------------------------------------------------------
__global__ __launch_bounds__(256) void mid_kernel(
    const float* __restrict__ hsF, const float* __restrict__ hsB,
    const float* __restrict__ cF0, const float* __restrict__ cB0,
    float* __restrict__ enc_out, short* __restrict__ enc_out_bf,
    short* __restrict__ hx0, float* __restrict__ cdec0)
{
    const int total = 64 * 64 * 512 + 64 * 512;
    for (int i = blockIdx.x * 256 + threadIdx.x; i < total; i += gridDim.x * 256) {
        if (i < 64 * 64 * 512) {
            int r = i >> 9, d = i & 511;
            int b = r >> 6, tt = r & 63;
            float v = hsF[(size_t)(tt * 64 + b) * 512 + d] + hsB[(size_t)(tt * 64 + b) * 512 + d];
            enc_out[i] = v;
            enc_out_bf[i] = f2bf(v);
        } else {
            int j = i - 64 * 64 * 512;
            int b = j >> 9, d = j & 511;
            float h0 = hsF[(size_t)(63 * 64 + b) * 512 + d] + hsB[(size_t)(0 * 64 + b) * 512 + d];
            hx0[b * 512 + d] = f2bf(h0);
            cdec0[b * 512 + d] = cF0[b * 512 + d] + cB0[b * 512 + d];
        }
    }
}

// ---------------------------------------------------------------------------
// scores[t][p][q] = v_b + sum_d tanh(enc_feat[p][q][d] + dec_f[t][p][d])*v_w[d]
// block = one (t,p); waves cover q.
// ---------------------------------------------------------------------------
__global__ __launch_bounds__(256) void attn_scores(
    const float* __restrict__ enc_feat, const float* __restrict__ dec_f,
    const float* __restrict__ v_w, const float* __restrict__ v_b,
    float* __restrict__ scores)
{
    int tp = blockIdx.x; // t*64+p
    int p = tp & 63;
    __shared__ float df[512], vw[512];
    for (int i = threadIdx.x; i < 512; i += 256) {
        df[i] = dec_f[(size_t)tp * 512 + i];
        vw[i] = v_w[i];
    }
    __syncthreads();
    int lane = threadIdx.x & 63, wave = threadIdx.x >> 6;
    float vb = v_b[0];
    for (int q = wave; q < 64; q += 4) {
        const float* ef = enc_feat + (size_t)(p * 64 + q) * 512;
        float s = 0.f;
        for (int d = lane; d < 512; d += 64)
            s += tanh_(ef[d] + df[d]) * vw[d];
        for (int o = 32; o > 0; o >>= 1) s += __shfl_xor(s, o);
        if (lane == 0) scores[(size_t)tp * 64 + q] = s + vb;
    }
}

// softmax over q per (t,p) row, then * mask (mask[p][q] = source[q][p]==PAD)
__global__ __launch_bounds__(256) void softmax_mask(
    float* __restrict__ attn, const int* __restrict__ source)
{
    int row = blockIdx.x * 4 + (threadIdx.x >> 6); // t*64+p, 0..3199
    int lane = threadIdx.x & 63;
    int p = row & 63;
    float v = attn[(size_t)row * 64 + lane];
    float m = v;
    for (int o = 32; o > 0; o >>= 1) m = fmaxf(m, __shfl_xor(m, o));
    float e = __expf(v - m);
    float s = e;
    for (int o = 32; o > 0; o >>= 1) s += __shfl_xor(s, o);
    float mask = (source[lane * 64 + p] == 0) ? 1.f : 0.f;
    attn[(size_t)row * 64 + lane] = (e / s) * mask;
}

// content[t][q][d] = sum_p attn[t][p][q] * enc_out[p][q][d]  -> cat left half
__global__ __launch_bounds__(256) void content_cat(
    const float* __restrict__ attn, const float* __restrict__ enc_out,
    short* __restrict__ cat)
{
    int tq = blockIdx.x; int q = tq & 63;
    __shared__ float ac[64];
    if (threadIdx.x < 64)
        ac[threadIdx.x] = attn[(size_t)((tq >> 6) * 64 + threadIdx.x) * 64 + q];
    __syncthreads();
    for (int d = threadIdx.x; d < 512; d += 256) {
        float s = 0.f;
#pragma unroll 8
        for (int pp = 0; pp < 64; ++pp)
            s += ac[pp] * enc_out[(size_t)(pp * 64 + q) * 512 + d];
        cat[(size_t)tq * 1024 + d] = f2bf(s);
    }
}

// per step t: lse per row, ce, valid-mask, mean, accumulate into d_out
__global__ __launch_bounds__(256) void loss_kernel(
    const float* __restrict__ partial, const float* __restrict__ tgtlog,
    const int* __restrict__ tgtf, float* __restrict__ out)
{
    int t = blockIdx.x;
    int tid = threadIdx.x;
    int b = tid >> 2, c = tid & 3;
    int row = t * 64 + b;
    float s = 0.f;
    for (int j = c; j < 2000; j += 4) s += partial[(size_t)row * 2000 + j];
    s += __shfl_xor(s, 1);
    s += __shfl_xor(s, 2);
    __shared__ float ce_s[64], va_s[64];
    if (c == 0) {
        float lse = logf(s);
        float ce = lse - tgtlog[row];
        float valid = (tgtf[row] != 0) ? 1.f : 0.f;
        ce_s[b] = ce * valid;
        va_s[b] = valid;
    }
    __syncthreads();
    if (tid < 64) {
        float cv = ce_s[tid], vv = va_s[tid];
        for (int o = 32; o > 0; o >>= 1) { cv += __shfl_xor(cv, o); vv += __shfl_xor(vv, o); }
        if (tid == 0) {
            float sl = (vv > 0.f) ? cv / fmaxf(vv, 1.f) : 0.f;
            atomicAdd(out, sl);
        }
    }
}

// ---------------------------------------------------------------------------
extern "C" void kernel_launch(void* const* d_in, const int* in_sizes, int n_in,
                              void* d_out, int out_size, void* d_ws, size_t ws_size,
                              hipStream_t stream)
{
    (void)in_sizes; (void)n_in; (void)out_size; (void)ws_size;
    const int*   source  = (const int*)  d_in[0];
    const int*   target  = (const int*)  d_in[1];
    const float* emb_src = (const float*)d_in[2];
    const float* emb_tgt = (const float*)d_in[3];
    const float* eWihF   = (const float*)d_in[4];
    const float* eWhhF   = (const float*)d_in[5];
    const float* ebihF   = (const float*)d_in[6];
    const float* ebhhF   = (const float*)d_in[7];
    const float* eWihB   = (const float*)d_in[8];
    const float* eWhhB   = (const float*)d_in[9];
    const float* ebihB   = (const float*)d_in[10];
    const float* ebhhB   = (const float*)d_in[11];
    const float* Wh_w    = (const float*)d_in[12];
    const float* Wh_b    = (const float*)d_in[13];
    const float* dWih    = (const float*)d_in[14];
    const float* dWhh    = (const float*)d_in[15];
    const float* dbih    = (const float*)d_in[16];
    const float* dbhh    = (const float*)d_in[17];
    const float* Ws_w    = (const float*)d_in[18];
    const float* Ws_b    = (const float*)d_in[19];
    const float* v_w     = (const float*)d_in[20];
    const float* v_b     = (const float*)d_in[21];
    const float* lin_w   = (const float*)d_in[22];
    const float* lin_b   = (const float*)d_in[23];
    const float* out_w   = (const float*)d_in[24];
    const float* out_b   = (const float*)d_in[25];

    char* base = (char*)d_ws;
    size_t off = 0;
    auto alloc = [&](size_t bytes) -> char* {
        char* p = base + off;
        off = (off + bytes + 255) & ~(size_t)255;
        return p;
    };
    // bf16 buffers
    short* WihF_bf = (short*)alloc(1048576ULL * 2);
    short* WhhF_bf = (short*)alloc(1048576ULL * 2);
    short* WihB_bf = (short*)alloc(1048576ULL * 2);
    short* WhhB_bf = (short*)alloc(1048576ULL * 2);
    short* WihD_bf = (short*)alloc(1048576ULL * 2);
    short* WhhD_bf = (short*)alloc(1048576ULL * 2);
    short* Ws_bf   = (short*)alloc(262144ULL * 2);
    short* Wh_bf   = (short*)alloc(262144ULL * 2);
    short* lin_bf  = (short*)alloc(524288ULL * 2);
    short* out_bf  = (short*)alloc(16384000ULL * 2);
    short* A_src   = (short*)alloc(2097152ULL * 2);
    short* A_tgt   = (short*)alloc(1638400ULL * 2);
    short* preF    = (short*)alloc(8388608ULL * 2);   // 4096 x 2048 (dead after encoder)
    short* preB    = (short*)alloc(8388608ULL * 2);   // 4096 x 2048 (dead after encoder)
    short* preD    = (short*)alloc(6553600ULL * 2);   // 3200 x 2048 (dead after decoder)
    short* hbfF    = (short*)alloc(65536ULL * 2);     // 2 slots x 64x512
    short* hbfB    = (short*)alloc(65536ULL * 2);
    short* hxbuf   = (short*)alloc(1671168ULL * 2);   // 51 x 64x512
    short* encout_bf = (short*)alloc(2097152ULL * 2); // 4096 x 512
    short* cat_bf  = (short*)alloc(3276800ULL * 2);   // 3200 x 1024
    short* hxnew   = (short*)alloc(1638400ULL * 2);   // 3200 x 512
    // fp32 buffers
    float* bsumF   = (float*)alloc(2048 * 4);
    float* bsumB   = (float*)alloc(2048 * 4);
    float* bsumD   = (float*)alloc(2048 * 4);
    float* cF      = (float*)alloc(65536ULL * 4);     // 2 slots
    float* cB      = (float*)alloc(65536ULL * 4);
    float* hsF     = (float*)alloc(2097152ULL * 4);   // (t*64+b)*512
    float* hsB     = (float*)alloc(2097152ULL * 4);
    float* enc_out = (float*)alloc(2097152ULL * 4);   // (b*64+t)*512
    float* enc_feat= (float*)alloc(2097152ULL * 4);
    float* cdec    = (float*)alloc(1671168ULL * 4);   // 51 x 64x512
    float* decf    = (float*)alloc(1638400ULL * 4);   // 3200 x 512
    float* attn    = (float*)alloc(204800ULL * 4);    // 3200 x 64
    float* tgtlog  = (float*)alloc(3200 * 4);
    int*   tgtf    = (int*)  alloc(3200 * 4);
    // partial (3200x2000 fp32 = 25.6 MB) aliases preF+preB (33.5 MB):
    // preF/preB are dead once the encoder loop finishes; partial is written
    // only in the logits GEMM, long after. Lifetimes are disjoint in every
    // launch, and addresses are fixed -> graph-capture safe.
    float* partial = (float*)preF;
    float* outp    = (float*)d_out;

    // ---- prep: converts/gathers/zeros ----
    PrepArgs P;
    P.Wih_f = eWihF; P.Whh_f = eWhhF; P.Wih_b = eWihB; P.Whh_b = eWhhB;
    P.Wih_d = dWih;  P.Whh_d = dWhh;
    P.oWih_f = WihF_bf; P.oWhh_f = WhhF_bf; P.oWih_b = WihB_bf; P.oWhh_b = WhhB_bf;
    P.oWih_d = WihD_bf; P.oWhh_d = WhhD_bf;
    P.Ws = Ws_w; P.Wh = Wh_w; P.lin = lin_w; P.outw = out_w;
    P.oWs = Ws_bf; P.oWh = Wh_bf; P.olin = lin_bf; P.oout = out_bf;
    P.emb_src = emb_src; P.emb_tgt = emb_tgt; P.source = source; P.target = target;
    P.A_src = A_src; P.A_tgt = A_tgt;
    P.bihf = ebihF; P.bhhf = ebhhF; P.bihb = ebihB; P.bhhb = ebhhB;
    P.bihd = dbih;  P.bhhd = dbhh;
    P.bsumf = bsumF; P.bsumb = bsumB; P.bsumd = bsumD;
    P.tgtf = tgtf;
    P.hbfF0 = hbfF; P.hbfB0 = hbfB; P.cF0 = cF; P.cB0 = cB;
    P.dout = outp;
    prep_kernel<<<dim3(2048), 256, 0, stream>>>(P);

    // ---- pre-GEMMs: x@Wih^T + biases for all timesteps (parallel) ----
    gemm_bt<8, 4><<<dim3(32, 32), 256, 0, stream>>>(A_src, 512, WihF_bf, 512, 512,
        bsumF, preF, 2048, nullptr, nullptr, nullptr);
    gemm_bt<8, 4><<<dim3(32, 32), 256, 0, stream>>>(A_src, 512, WihB_bf, 512, 512,
        bsumB, preB, 2048, nullptr, nullptr, nullptr);
    gemm_bt<8, 4><<<dim3(25, 32), 256, 0, stream>>>(A_tgt, 512, WihD_bf, 512, 512,
        bsumD, preD, 2048, nullptr, nullptr, nullptr);

    // ---- encoder recurrence: 64 steps, fwd+bwd in one launch ----
    for (int s = 0; s < 64; ++s) {
        int tf = s, tb = 63 - s;
        StepArgs aF, aB;
        aF.A = hbfF + (s & 1) * 32768; aF.B = WhhF_bf;
        aF.pre = preF + (size_t)tf * 64 * 2048;
        aF.cprev = cF + (s & 1) * 32768; aF.cnext = cF + ((s + 1) & 1) * 32768;
        aF.h1 = hbfF + ((s + 1) & 1) * 32768; aF.ldh1 = 512;
        aF.h2 = nullptr; aF.ldh2 = 0;
        aF.hs = hsF + (size_t)tf * 64 * 512;
        aB.A = hbfB + (s & 1) * 32768; aB.B = WhhB_bf;
        aB.pre = preB + (size_t)tb * 64 * 2048;
        aB.cprev = cB + (s & 1) * 32768; aB.cnext = cB + ((s + 1) & 1) * 32768;
        aB.h1 = hbfB + ((s + 1) & 1) * 32768; aB.ldh1 = 512;
        aB.h2 = nullptr; aB.ldh2 = 0;
        aB.hs = hsB + (size_t)tb * 64 * 512;
        lstm_step<<<dim3(32, 2), 256, 0, stream>>>(aF, aB);
    }

    // ---- mid: enc_out (+bf16), decoder initial state ----
    mid_kernel<<<dim3(1024), 256, 0, stream>>>(hsF, hsB, cF, cB,
        enc_out, encout_bf, hxbuf, cdec);

    // ---- enc_feat = enc_out @ Wh^T + Wh_b ----
    gemm_bt<8, 0><<<dim3(32, 8), 256, 0, stream>>>(encout_bf, 512, Wh_bf, 512, 512,
        Wh_b, enc_feat, 512, nullptr, nullptr, nullptr);

    // ---- decoder recurrence: 50 steps (LSTM only; heads are batched later) ----
    for (int t = 1; t <= 50; ++t) {
        StepArgs aD;
        aD.A = hxbuf + (size_t)(t - 1) * 32768; aD.B = WhhD_bf;
        aD.pre = preD + (size_t)(t - 1) * 64 * 2048;
        aD.cprev = cdec + (size_t)(t - 1) * 32768; aD.cnext = cdec + (size_t)t * 32768;
        aD.h1 = hxbuf + (size_t)t * 32768; aD.ldh1 = 512;
        aD.h2 = cat_bf + (size_t)(t - 1) * 64 * 1024 + 512; aD.ldh2 = 1024;
        aD.hs = nullptr;
        lstm_step<<<dim3(32, 1), 256, 0, stream>>>(aD, aD);
    }

    // ---- batched heads over all 50 steps ----
    // dec_f = hx @ Ws^T + Ws_b   (M=3200)
    gemm_bt<8, 0><<<dim3(25, 8), 256, 0, stream>>>(hxbuf + 32768, 512, Ws_bf, 512, 512,
        Ws_b, decf, 512, nullptr, nullptr, nullptr);
    // scores
    attn_scores<<<dim3(3200), 256, 0, stream>>>(enc_feat, decf, v_w, v_b, attn);
    // softmax * pad-mask (reference's transposed-mask semantics)
    softmax_mask<<<dim3(800), 256, 0, stream>>>(attn, source);
    // content (reference's reshape-scrambled semantics) -> cat left half
    content_cat<<<dim3(3200), 256, 0, stream>>>(attn, enc_out, cat_bf);
    // hx_new = tanh(cat @ lin^T + lin_b) -> bf16
    gemm_bt<8, 1><<<dim3(25, 8), 256, 0, stream>>>(cat_bf, 1024, lin_bf, 1024, 1024,
        lin_b, hxnew, 512, nullptr, nullptr, nullptr);
    // logits GEMM fused with LSE partials + target-logit grab
    gemm_bt<8, 3><<<dim3(25, 500), 256, 0, stream>>>(hxnew, 512, out_bf, 512, 512,
        out_b, nullptr, 0, partial, tgtf, tgtlog);
    // per-step CE means, summed into d_out
    loss_kernel<<<dim3(50), 256, 0, stream>>>(partial, tgtlog, tgtf, outp);
}

// Round 6
// 1527.662 us; speedup vs baseline: 2.0422x; 2.0422x over previous
//
#include <hip/hip_runtime.h>

// ---------------------------------------------------------------------------
// EncoderDecoder (bi-LSTM encoder + attention decoder + CE loss), MI355X.
// R3 profile: logits GEMM 904us latency-bound (MfmaUtil 4.7%); 114 sequential
// lstm_step launches ~1.7ms aggregate. R4: (1) m97-structure LDS GEMM
// (global_load_lds w16, BK=64, XOR swizzle) for all big GEMMs; (2) persistent
// encoder/decoder kernels (1 launch each) with device-scope atomic grid
// barrier, Whh register-resident, c-state register-resident.
// ---------------------------------------------------------------------------

#define DI __device__ __forceinline__

typedef __attribute__((ext_vector_type(8))) short bf16x8;
typedef __attribute__((ext_vector_type(4))) short s16x4;
typedef __attribute__((ext_vector_type(4))) float f32x4;
typedef const __attribute__((address_space(1))) void* gp1_t;
typedef __attribute__((address_space(3))) void* lp3_t;

DI float bf2f(short u) {
    union { float f; unsigned u; } c; c.u = ((unsigned)(unsigned short)u) << 16; return c.f;
}
DI short f2bf(float f) {
    union { float f; unsigned u; } c; c.f = f;
    unsigned r = c.u + 0x7fffu + ((c.u >> 16) & 1u);
    return (short)(r >> 16);
}
DI float sigm(float x) { return 1.f / (1.f + __expf(-x)); }
DI float tanh_(float x) {
    float e = __expf(-2.f * fabsf(x));
    float r = (1.f - e) / (1.f + e);
    return copysignf(r, x);
}

// ---------------------------------------------------------------------------
// m97-structure GEMM: C[m][n] = sum_k A[m][k]*B[n][k], row-major, K contig.
// 128x128 tile, BK=64, 4 waves (2x2), 4x4 16x16x32 frags/wave, single-buffer
// LDS with global_load_lds(16B) staging, XOR slot swizzle (slot ^= row&7).
// EPI 0: f32 C=v+bias. EPI 1: bf16 C=tanh(v+bias). EPI 4: bf16 C=v+bias.
// EPI 3: partial[row*pstride + bx*2 + wc] = sum_16cols exp(v+bias).
// ---------------------------------------------------------------------------
template<int EPI>
__global__ __launch_bounds__(256) void gemm128(
    const short* __restrict__ A, int lda,
    const short* __restrict__ B, int ldb,
    int K,
    const float* __restrict__ bias,
    void* __restrict__ Cout, int ldc,
    float* __restrict__ partial, int pstride)
{
    __shared__ short lA[8192], lB[8192]; // 16KB each: [128 rows][128B], swizzled slots
    const int tid = threadIdx.x;
    const int lane = tid & 63, wave = tid >> 6;
    const int wr = wave >> 1, wc = wave & 1;
    const int mbase = blockIdx.y * 128, nbase = blockIdx.x * 128;

    // staging sources: 4 rounds A + 4 rounds B, 16B per thread per round.
    // round R: row = R*32 + (tid>>3), slot = tid&7; src slot pre-XORed so the
    // linear LDS dest holds the swizzled arrangement (G21: inverse-swz source).
    const char* ga[4]; const char* gb[4];
    {
        int r = tid >> 3, sl = tid & 7;
#pragma unroll
        for (int R = 0; R < 4; ++R) {
            int row = R * 32 + r;
            int so = (sl ^ (row & 7)) << 4;
            ga[R] = (const char*)(A + (size_t)(mbase + row) * lda) + so;
            gb[R] = (const char*)(B + (size_t)(nbase + row) * ldb) + so;
        }
    }
    const int r7 = lane & 7, gq = lane >> 4;
    int abase[4], bbase[4];
#pragma unroll
    for (int i = 0; i < 4; ++i) {
        abase[i] = (wr * 64 + i * 16 + (lane & 15)) * 128;
        bbase[i] = (wc * 64 + i * 16 + (lane & 15)) * 128;
    }
    int sloff[2];
#pragma unroll
    for (int h = 0; h < 2; ++h) sloff[h] = ((h * 4 + gq) ^ r7) << 4;

    f32x4 acc[4][4];
#pragma unroll
    for (int i = 0; i < 4; ++i)
#pragma unroll
        for (int j = 0; j < 4; ++j) acc[i][j] = (f32x4){0.f, 0.f, 0.f, 0.f};

    for (int kk = 0; kk < K; kk += 64) {
#pragma unroll
        for (int R = 0; R < 4; ++R)
            __builtin_amdgcn_global_load_lds((gp1_t)ga[R],
                (lp3_t)((char*)lA + R * 4096 + tid * 16), 16, 0, 0);
#pragma unroll
        for (int R = 0; R < 4; ++R)
            __builtin_amdgcn_global_load_lds((gp1_t)gb[R],
                (lp3_t)((char*)lB + R * 4096 + tid * 16), 16, 0, 0);
#pragma unroll
        for (int R = 0; R < 4; ++R) { ga[R] += 128; gb[R] += 128; }
        __syncthreads(); // compiler emits vmcnt(0) drain before barrier
#pragma unroll
        for (int h = 0; h < 2; ++h) {
            bf16x8 af[4], bfv[4];
#pragma unroll
            for (int i = 0; i < 4; ++i)
                af[i] = *(const bf16x8*)((const char*)lA + abase[i] + sloff[h]);
#pragma unroll
            for (int j = 0; j < 4; ++j)
                bfv[j] = *(const bf16x8*)((const char*)lB + bbase[j] + sloff[h]);
#pragma unroll
            for (int i = 0; i < 4; ++i)
#pragma unroll
                for (int j = 0; j < 4; ++j)
                    acc[i][j] = __builtin_amdgcn_mfma_f32_16x16x32_bf16(
                        af[i], bfv[j], acc[i][j], 0, 0, 0);
        }
        __syncthreads();
    }

    float bv[4];
#pragma unroll
    for (int j = 0; j < 4; ++j) bv[j] = bias[nbase + wc * 64 + j * 16 + (lane & 15)];

    if constexpr (EPI == 3) {
#pragma unroll
        for (int i = 0; i < 4; ++i)
#pragma unroll
            for (int r = 0; r < 4; ++r) {
                float es = 0.f;
#pragma unroll
                for (int j = 0; j < 4; ++j) es += __expf(acc[i][j][r] + bv[j]);
                es += __shfl_xor(es, 1); es += __shfl_xor(es, 2);
                es += __shfl_xor(es, 4); es += __shfl_xor(es, 8);
                if ((lane & 15) == 0) {
                    int row = mbase + wr * 64 + i * 16 + (lane >> 4) * 4 + r;
                    partial[(size_t)row * pstride + blockIdx.x * 2 + wc] = es;
                }
            }
    } else {
#pragma unroll
        for (int i = 0; i < 4; ++i)
#pragma unroll
            for (int j = 0; j < 4; ++j)
#pragma unroll
                for (int r = 0; r < 4; ++r) {
                    int row = mbase + wr * 64 + i * 16 + (lane >> 4) * 4 + r;
                    int col = nbase + wc * 64 + j * 16 + (lane & 15);
                    float v = acc[i][j][r] + bv[j];
                    if constexpr (EPI == 0)
                        ((float*)Cout)[(size_t)row * ldc + col] = v;
                    else if constexpr (EPI == 1)
                        ((short*)Cout)[(size_t)row * ldc + col] = f2bf(tanh_(v));
                    else
                        ((short*)Cout)[(size_t)row * ldc + col] = f2bf(v);
                }
    }
}

// ---------------------------------------------------------------------------
// Device-scope grid barrier (monotonic counter, no reset; zeroed by prep).
// All blocks guaranteed co-resident (<=64 blocks on 256 CUs).
// ---------------------------------------------------------------------------
DI void gbar(int* bar, int target)
{
    __syncthreads();
    if (threadIdx.x == 0) {
        __threadfence();                 // release: my block's writes visible
        atomicAdd(bar, 1);               // device-scope
        while (__hip_atomic_load(bar, __ATOMIC_RELAXED, __HIP_MEMORY_SCOPE_AGENT) < target)
            __builtin_amdgcn_s_sleep(2);
        __threadfence();                 // acquire: others' writes visible
    }
    __syncthreads();
}

// ---------------------------------------------------------------------------
// Persistent encoder: 64 blocks (32 fwd + 32 bwd), 64 steps in one launch.
// Per block: 64 cols of the gate space (16 h-idx), Whh frags in regs (64 VGPR),
// c-state in regs, h staged to LDS each step via swizzled-source gload_lds.
// h slots are fresh addresses per step (no reuse -> no stale-line hazard).
// ---------------------------------------------------------------------------
struct EncDir {
    const short* Whh;   // permuted 2048x512 bf16
    const short* pre;   // [64 t][64 b][2048] bf16 (bias folded)
    short* hslots;      // 65 slots x (64x512) bf16; slot s = h after step s
    float* hs;          // fp32 (t*64+b)*512
    float* cfin;        // 64x512 f32 final cell state
};

__global__ __launch_bounds__(256) void enc_kernel(EncDir F, EncDir Bd, int* bar)
{
    const int isB = (blockIdx.x >= 32) ? 1 : 0;
    const EncDir E = isB ? Bd : F;
    const int nb = blockIdx.x & 31;
    const int tid = threadIdx.x, lane = tid & 63, wave = tid >> 6;
    const int lc = wave * 16 + (lane & 15);
    const int ncol = nb * 64 + lc;

    bf16x8 bq[16];
    {
        const short* bp = E.Whh + (size_t)ncol * 512 + ((lane >> 4) * 8);
#pragma unroll
        for (int ks = 0; ks < 16; ++ks) bq[ks] = *(const bf16x8*)(bp + ks * 32);
    }
    float cr[4] = {0.f, 0.f, 0.f, 0.f};

    __shared__ short hl[32768];   // 64KB staged h (swizzled slots)
    __shared__ float g[64 * 65];  // gate transpose, +1 pad

    const int swave = tid >> 6, ssl = tid & 63;
    const int r7 = lane & 7, gq = lane >> 4;
    const int hb_base = (lane & 15) << 10;

    for (int s = 0; s < 64; ++s) {
        const char* hsrc = (const char*)E.hslots + (size_t)s * 65536;
#pragma unroll
        for (int R = 0; R < 16; ++R) {
            int row = R * 4 + swave; // wave-uniform row, lanes cover 64 slots
            __builtin_amdgcn_global_load_lds(
                (gp1_t)(hsrc + row * 1024 + ((ssl ^ (row & 7)) << 4)),
                (lp3_t)((char*)hl + R * 4096 + tid * 16), 16, 0, 0);
        }
        __syncthreads();

        f32x4 acc[4];
#pragma unroll
        for (int i = 0; i < 4; ++i) acc[i] = (f32x4){0.f, 0.f, 0.f, 0.f};
#pragma unroll
        for (int ks = 0; ks < 16; ++ks) {
            const char* hb = (const char*)hl + hb_base + (((ks * 4 + gq) ^ r7) << 4);
#pragma unroll
            for (int mt = 0; mt < 4; ++mt)
                acc[mt] = __builtin_amdgcn_mfma_f32_16x16x32_bf16(
                    *(const bf16x8*)(hb + mt * 16384), bq[ks], acc[mt], 0, 0, 0);
        }
#pragma unroll
        for (int mt = 0; mt < 4; ++mt)
#pragma unroll
            for (int r = 0; r < 4; ++r)
                g[(mt * 16 + gq * 4 + r) * 65 + lc] = acc[mt][r];
        __syncthreads();

        const int tf = isB ? (63 - s) : s;
        const short* prr = E.pre + (size_t)tf * 131072;
        short* hw = E.hslots + (size_t)(s + 1) * 32768;
        float* hsw = E.hs + (size_t)tf * 32768;
#pragma unroll
        for (int it = 0; it < 4; ++it) {
            int item = tid + it * 256, b = item >> 4, jj = item & 15;
            int j = nb * 16 + jj;
            s16x4 pv = *(const s16x4*)(prr + b * 2048 + nb * 64 + jj * 4);
            float gi = g[b * 65 + jj * 4 + 0] + bf2f(pv.x);
            float gf = g[b * 65 + jj * 4 + 1] + bf2f(pv.y);
            float gg = g[b * 65 + jj * 4 + 2] + bf2f(pv.z);
            float go = g[b * 65 + jj * 4 + 3] + bf2f(pv.w);
            float cn = sigm(gf) * cr[it] + sigm(gi) * tanh_(gg);
            float h = sigm(go) * tanh_(cn);
            cr[it] = cn;
            hw[b * 512 + j] = f2bf(h);
            hsw[b * 512 + j] = h;
            if (s == 63) E.cfin[b * 512 + j] = cn;
        }
        gbar(bar, 64 * (s + 1));
    }
}

// ---------------------------------------------------------------------------
// Persistent decoder: 32 blocks, 50 steps. Same structure; also writes the
// cat right-half; c0 from mid_kernel; h slots = hxbuf (plain, read later by
// the dec_f GEMM).
// ---------------------------------------------------------------------------
__global__ __launch_bounds__(256) void dec_kernel(
    const short* __restrict__ Whh, const short* __restrict__ pre,
    short* __restrict__ hslots, const float* __restrict__ c0,
    short* __restrict__ cat, int* __restrict__ bar)
{
    const int nb = blockIdx.x;
    const int tid = threadIdx.x, lane = tid & 63, wave = tid >> 6;
    const int lc = wave * 16 + (lane & 15);
    const int ncol = nb * 64 + lc;

    bf16x8 bq[16];
    {
        const short* bp = Whh + (size_t)ncol * 512 + ((lane >> 4) * 8);
#pragma unroll
        for (int ks = 0; ks < 16; ++ks) bq[ks] = *(const bf16x8*)(bp + ks * 32);
    }
    float cr[4];
#pragma unroll
    for (int it = 0; it < 4; ++it) {
        int item = tid + it * 256, b = item >> 4, jj = item & 15;
        cr[it] = c0[b * 512 + nb * 16 + jj];
    }

    __shared__ short hl[32768];
    __shared__ float g[64 * 65];
    const int swave = tid >> 6, ssl = tid & 63;
    const int r7 = lane & 7, gq = lane >> 4;
    const int hb_base = (lane & 15) << 10;

    for (int t = 0; t < 50; ++t) {
        const char* hsrc = (const char*)hslots + (size_t)t * 65536;
#pragma unroll
        for (int R = 0; R < 16; ++R) {
            int row = R * 4 + swave;
            __builtin_amdgcn_global_load_lds(
                (gp1_t)(hsrc + row * 1024 + ((ssl ^ (row & 7)) << 4)),
                (lp3_t)((char*)hl + R * 4096 + tid * 16), 16, 0, 0);
        }
        __syncthreads();

        f32x4 acc[4];
#pragma unroll
        for (int i = 0; i < 4; ++i) acc[i] = (f32x4){0.f, 0.f, 0.f, 0.f};
#pragma unroll
        for (int ks = 0; ks < 16; ++ks) {
            const char* hb = (const char*)hl + hb_base + (((ks * 4 + gq) ^ r7) << 4);
#pragma unroll
            for (int mt = 0; mt < 4; ++mt)
                acc[mt] = __builtin_amdgcn_mfma_f32_16x16x32_bf16(
                    *(const bf16x8*)(hb + mt * 16384), bq[ks], acc[mt], 0, 0, 0);
        }
#pragma unroll
        for (int mt = 0; mt < 4; ++mt)
#pragma unroll
            for (int r = 0; r < 4; ++r)
                g[(mt * 16 + gq * 4 + r) * 65 + lc] = acc[mt][r];
        __syncthreads();

        const short* prr = pre + (size_t)t * 131072;
        short* hw = hslots + (size_t)(t + 1) * 32768;
        short* cw = cat + (size_t)t * 65536 + 512;
#pragma unroll
        for (int it = 0; it < 4; ++it) {
            int item = tid + it * 256, b = item >> 4, jj = item & 15;
            int j = nb * 16 + jj;
            s16x4 pv = *(const s16x4*)(prr + b * 2048 + nb * 64 + jj * 4);
            float gi = g[b * 65 + jj * 4 + 0] + bf2f(pv.x);
            float gf = g[b * 65 + jj * 4 + 1] + bf2f(pv.y);
            float gg = g[b * 65 + jj * 4 + 2] + bf2f(pv.z);
            float go = g[b * 65 + jj * 4 + 3] + bf2f(pv.w);
            float cn = sigm(gf) * cr[it] + sigm(gi) * tanh_(gg);
            float h = sigm(go) * tanh_(cn);
            cr[it] = cn;
            hw[b * 512 + j] = f2bf(h);
            cw[b * 1024 + j] = f2bf(h);
        }
        gbar(bar, 32 * (t + 1));
    }
}

// ---------------------------------------------------------------------------
// prep: weight conversion/permutation, embedding gathers, bias sums, tgt
// indices, zero-init (h slot 0, d_out, barrier counters).
// ---------------------------------------------------------------------------
struct PrepArgs {
    const float *Wih_f, *Whh_f, *Wih_b, *Whh_b, *Wih_d, *Whh_d;
    short *oWih_f, *oWhh_f, *oWih_b, *oWhh_b, *oWih_d, *oWhh_d;
    const float *Ws, *Wh, *lin, *outw;
    short *oWs, *oWh, *olin, *oout;
    const float *emb_src, *emb_tgt;
    const int *source, *target;
    short *A_src, *A_tgt;
    const float *bihf, *bhhf, *bihb, *bhhb, *bihd, *bhhd;
    float *bsumf, *bsumb, *bsumd;
    int *tgtf;
    short *hF0, *hB0;   // encoder h slot 0 (32768 shorts each)
    float *dout;
    int *bar;           // 2 counters
};

__global__ __launch_bounds__(256) void prep_kernel(PrepArgs P)
{
    const long long total = 6291456LL + 262144 + 262144 + 524288 + 16384000
                          + 2097152 + 1638400 + 6144 + 3200 + 65536 + 3;
    for (long long i = (long long)blockIdx.x * 256 + threadIdx.x; i < total;
         i += (long long)gridDim.x * 256) {
        long long t = i;
        if (t < 6291456LL) {
            int seg = (int)(t >> 20); int r = (int)(t & 1048575);
            int n = r >> 9, k = r & 511;
            int orig = (n & 3) * 512 + (n >> 2);
            const float* s; short* d;
            switch (seg) {
                case 0: s = P.Wih_f; d = P.oWih_f; break;
                case 1: s = P.Whh_f; d = P.oWhh_f; break;
                case 2: s = P.Wih_b; d = P.oWih_b; break;
                case 3: s = P.Whh_b; d = P.oWhh_b; break;
                case 4: s = P.Wih_d; d = P.oWih_d; break;
                default: s = P.Whh_d; d = P.oWhh_d; break;
            }
            d[n * 512 + k] = f2bf(s[orig * 512 + k]);
            continue;
        }
        t -= 6291456LL;
        if (t < 262144) { P.oWs[t] = f2bf(P.Ws[t]); continue; } t -= 262144;
        if (t < 262144) { P.oWh[t] = f2bf(P.Wh[t]); continue; } t -= 262144;
        if (t < 524288) { P.olin[t] = f2bf(P.lin[t]); continue; } t -= 524288;
        if (t < 16384000) { P.oout[t] = f2bf(P.outw[t]); continue; } t -= 16384000;
        if (t < 2097152) {
            int r = (int)(t >> 9), k = (int)(t & 511);
            int tt = r >> 6, b = r & 63;
            int tok = P.source[b * 64 + tt];
            P.A_src[t] = tok ? f2bf(P.emb_src[(size_t)tok * 512 + k]) : (short)0;
            continue;
        } t -= 2097152;
        if (t < 1638400) {
            int r = (int)(t >> 9), k = (int)(t & 511);
            int tt = r >> 6, b = r & 63;
            int tok = P.target[b * 51 + tt];
            P.A_tgt[t] = tok ? f2bf(P.emb_tgt[(size_t)tok * 512 + k]) : (short)0;
            continue;
        } t -= 1638400;
        if (t < 6144) {
            int net = (int)(t >> 11); int n = (int)(t & 2047);
            int orig = (n & 3) * 512 + (n >> 2);
            if (net == 0)      P.bsumf[n] = P.bihf[orig] + P.bhhf[orig];
            else if (net == 1) P.bsumb[n] = P.bihb[orig] + P.bhhb[orig];
            else               P.bsumd[n] = P.bihd[orig] + P.bhhd[orig];
            continue;
        } t -= 6144;
        if (t < 3200) {
            int s = (int)t >> 6, b = (int)t & 63;
            P.tgtf[t] = P.target[b * 51 + s + 1];
            continue;
        } t -= 3200;
        if (t < 65536) {
            if (t < 32768) P.hF0[t] = 0; else P.hB0[t - 32768] = 0;
            continue;
        } t -= 65536;
        if (t == 0) P.dout[0] = 0.f;
        else P.bar[t - 1] = 0;
    }
}

// ---------------------------------------------------------------------------
// mid: enc_out = hs_f + hs_b (fp32 + bf16), decoder initial state.
// ---------------------------------------------------------------------------
__global__ __launch_bounds__(256) void mid_kernel(
    const float* __restrict__ hsF, const float* __restrict__ hsB,
    const float* __restrict__ cFf, const float* __restrict__ cBf,
    float* __restrict__ enc_out, short* __restrict__ enc_out_bf,
    short* __restrict__ hx0, float* __restrict__ cdec0)
{
    const int total = 64 * 64 * 512 + 64 * 512;
    for (int i = blockIdx.x * 256 + threadIdx.x; i < total; i += gridDim.x * 256) {
        if (i < 64 * 64 * 512) {
            int r = i >> 9, d = i & 511;
            int b = r >> 6, tt = r & 63;
            float v = hsF[(size_t)(tt * 64 + b) * 512 + d] + hsB[(size_t)(tt * 64 + b) * 512 + d];
            enc_out[i] = v;
            enc_out_bf[i] = f2bf(v);
        } else {
            int j = i - 64 * 64 * 512;
            int b = j >> 9, d = j & 511;
            float h0 = hsF[(size_t)(63 * 64 + b) * 512 + d] + hsB[(size_t)(0 * 64 + b) * 512 + d];
            hx0[b * 512 + d] = f2bf(h0);
            cdec0[b * 512 + d] = cFf[b * 512 + d] + cBf[b * 512 + d];
        }
    }
}

// ---------------------------------------------------------------------------
// scores[t][p][q] = v_b + sum_d tanh(enc_feat[p][q][d] + dec_f[t][p][d])*v_w[d]
// grid (50, 64): consecutive blocks share p -> enc_feat chunk hot in L2.
// ---------------------------------------------------------------------------
__global__ __launch_bounds__(256) void attn_scores(
    const float* __restrict__ enc_feat, const float* __restrict__ dec_f,
    const float* __restrict__ v_w, const float* __restrict__ v_b,
    float* __restrict__ scores)
{
    int p = blockIdx.y;
    int tp = blockIdx.x * 64 + p;
    __shared__ float df[512], vw[512];
    for (int i = threadIdx.x; i < 512; i += 256) {
        df[i] = dec_f[(size_t)tp * 512 + i];
        vw[i] = v_w[i];
    }
    __syncthreads();
    int lane = threadIdx.x & 63, wave = threadIdx.x >> 6;
    float vb = v_b[0];
    for (int q = wave; q < 64; q += 4) {
        const float* ef = enc_feat + (size_t)(p * 64 + q) * 512;
        float s = 0.f;
        for (int d = lane; d < 512; d += 64)
            s += tanh_(ef[d] + df[d]) * vw[d];
        for (int o = 32; o > 0; o >>= 1) s += __shfl_xor(s, o);
        if (lane == 0) scores[(size_t)tp * 64 + q] = s + vb;
    }
}

__global__ __launch_bounds__(256) void softmax_mask(
    float* __restrict__ attn, const int* __restrict__ source)
{
    int row = blockIdx.x * 4 + (threadIdx.x >> 6);
    int lane = threadIdx.x & 63;
    int p = row & 63;
    float v = attn[(size_t)row * 64 + lane];
    float m = v;
    for (int o = 32; o > 0; o >>= 1) m = fmaxf(m, __shfl_xor(m, o));
    float e = __expf(v - m);
    float s = e;
    for (int o = 32; o > 0; o >>= 1) s += __shfl_xor(s, o);
    float mask = (source[lane * 64 + p] == 0) ? 1.f : 0.f;
    attn[(size_t)row * 64 + lane] = (e / s) * mask;
}

// content[t][q][d] = sum_p attn[t][p][q] * enc_out[p][q][d]; grid (50, 64)
__global__ __launch_bounds__(256) void content_cat(
    const float* __restrict__ attn, const float* __restrict__ enc_out,
    short* __restrict__ cat)
{
    int q = blockIdx.y;
    int tq = blockIdx.x * 64 + q;
    __shared__ float ac[64];
    if (threadIdx.x < 64)
        ac[threadIdx.x] = attn[(size_t)(blockIdx.x * 64 + threadIdx.x) * 64 + q];
    __syncthreads();
    for (int d = threadIdx.x; d < 512; d += 256) {
        float s = 0.f;
#pragma unroll 8
        for (int pp = 0; pp < 64; ++pp)
            s += ac[pp] * enc_out[(size_t)(pp * 64 + q) * 512 + d];
        cat[(size_t)tq * 1024 + d] = f2bf(s);
    }
}

// per step t: lse per row (500 partials), target logit via 512-dot, CE, mean.
__global__ __launch_bounds__(256) void loss_kernel(
    const float* __restrict__ partial, const short* __restrict__ hxnew,
    const short* __restrict__ outw, const float* __restrict__ outb,
    const int* __restrict__ tgtf, float* __restrict__ out)
{
    int t = blockIdx.x;
    int tid = threadIdx.x;
    int b = tid >> 2, c = tid & 3;
    int row = t * 64 + b;
    float s = 0.f;
    for (int j = c; j < 500; j += 4) s += partial[(size_t)row * 500 + j];
    int w = tgtf[row];
    const short* hp = hxnew + (size_t)row * 512 + c * 128;
    const short* wp = outw + (size_t)w * 512 + c * 128;
    float tl = 0.f;
    for (int k2 = 0; k2 < 128; k2 += 8) {
        bf16x8 hv = *(const bf16x8*)(hp + k2);
        bf16x8 wv = *(const bf16x8*)(wp + k2);
#pragma unroll
        for (int u = 0; u < 8; ++u) tl += bf2f(hv[u]) * bf2f(wv[u]);
    }
    s += __shfl_xor(s, 1); s += __shfl_xor(s, 2);
    tl += __shfl_xor(tl, 1); tl += __shfl_xor(tl, 2);
    __shared__ float ce_s[64], va_s[64];
    if (c == 0) {
        float lse = logf(s);
        float ce = lse - (tl + outb[w]);
        float valid = (w != 0) ? 1.f : 0.f;
        ce_s[b] = ce * valid;
        va_s[b] = valid;
    }
    __syncthreads();
    if (tid < 64) {
        float cv = ce_s[tid], vv = va_s[tid];
        for (int o = 32; o > 0; o >>= 1) { cv += __shfl_xor(cv, o); vv += __shfl_xor(vv, o); }
        if (tid == 0) {
            float sl = (vv > 0.f) ? cv / fmaxf(vv, 1.f) : 0.f;
            atomicAdd(out, sl);
        }
    }
}

// ---------------------------------------------------------------------------
extern "C" void kernel_launch(void* const* d_in, const int* in_sizes, int n_in,
                              void* d_out, int out_size, void* d_ws, size_t ws_size,
                              hipStream_t stream)
{
    (void)in_sizes; (void)n_in; (void)out_size; (void)ws_size;
    const int*   source  = (const int*)  d_in[0];
    const int*   target  = (const int*)  d_in[1];
    const float* emb_src = (const float*)d_in[2];
    const float* emb_tgt = (const float*)d_in[3];
    const float* eWihF   = (const float*)d_in[4];
    const float* eWhhF   = (const float*)d_in[5];
    const float* ebihF   = (const float*)d_in[6];
    const float* ebhhF   = (const float*)d_in[7];
    const float* eWihB   = (const float*)d_in[8];
    const float* eWhhB   = (const float*)d_in[9];
    const float* ebihB   = (const float*)d_in[10];
    const float* ebhhB   = (const float*)d_in[11];
    const float* Wh_w    = (const float*)d_in[12];
    const float* Wh_b    = (const float*)d_in[13];
    const float* dWih    = (const float*)d_in[14];
    const float* dWhh    = (const float*)d_in[15];
    const float* dbih    = (const float*)d_in[16];
    const float* dbhh    = (const float*)d_in[17];
    const float* Ws_w    = (const float*)d_in[18];
    const float* Ws_b    = (const float*)d_in[19];
    const float* v_w     = (const float*)d_in[20];
    const float* v_b     = (const float*)d_in[21];
    const float* lin_w   = (const float*)d_in[22];
    const float* lin_b   = (const float*)d_in[23];
    const float* out_w   = (const float*)d_in[24];
    const float* out_b   = (const float*)d_in[25];

    char* base = (char*)d_ws;
    size_t off = 0;
    auto alloc = [&](size_t bytes) -> char* {
        char* p = base + off;
        off = (off + bytes + 255) & ~(size_t)255;
        return p;
    };
    // bf16 buffers
    short* WihF_bf = (short*)alloc(1048576ULL * 2);
    short* WhhF_bf = (short*)alloc(1048576ULL * 2);
    short* WihB_bf = (short*)alloc(1048576ULL * 2);
    short* WhhB_bf = (short*)alloc(1048576ULL * 2);
    short* WihD_bf = (short*)alloc(1048576ULL * 2);
    short* WhhD_bf = (short*)alloc(1048576ULL * 2);
    short* Ws_bf   = (short*)alloc(262144ULL * 2);
    short* Wh_bf   = (short*)alloc(262144ULL * 2);
    short* lin_bf  = (short*)alloc(524288ULL * 2);
    short* out_bf  = (short*)alloc(16384000ULL * 2);
    short* A_src   = (short*)alloc(2097152ULL * 2);
    short* A_tgt   = (short*)alloc(1638400ULL * 2);
    short* preF    = (short*)alloc(8388608ULL * 2);   // 64x64x2048, dead after enc
    short* preB    = (short*)alloc(8388608ULL * 2);
    short* preD    = (short*)alloc(6553600ULL * 2);   // 50x64x2048
    short* hF_sl   = (short*)alloc(65ULL * 32768 * 2); // 65 h slots fwd
    short* hB_sl   = (short*)alloc(65ULL * 32768 * 2);
    short* hxbuf   = (short*)alloc(51ULL * 32768 * 2); // decoder h slots
    short* encout_bf = (short*)alloc(2097152ULL * 2);
    short* cat_bf  = (short*)alloc(3276800ULL * 2);   // 3200x1024
    short* hxnew   = (short*)alloc(1638400ULL * 2);
    // fp32 buffers
    float* bsumF   = (float*)alloc(2048 * 4);
    float* bsumB   = (float*)alloc(2048 * 4);
    float* bsumD   = (float*)alloc(2048 * 4);
    float* cFf     = (float*)alloc(32768ULL * 4);
    float* cBf     = (float*)alloc(32768ULL * 4);
    float* cdec0   = (float*)alloc(32768ULL * 4);
    float* hsF     = (float*)alloc(2097152ULL * 4);
    float* hsB     = (float*)alloc(2097152ULL * 4);
    float* enc_out = (float*)alloc(2097152ULL * 4);
    float* enc_feat= (float*)alloc(2097152ULL * 4);
    float* decf    = (float*)alloc(1638400ULL * 4);
    float* attn    = (float*)alloc(204800ULL * 4);
    int*   tgtf    = (int*)  alloc(3200 * 4);
    int*   bar     = (int*)  alloc(16);
    // partial (3200x500 f32 = 6.4MB) aliases preF (16.8MB, dead after encoder)
    float* partial = (float*)preF;
    float* outp    = (float*)d_out;

    PrepArgs P;
    P.Wih_f = eWihF; P.Whh_f = eWhhF; P.Wih_b = eWihB; P.Whh_b = eWhhB;
    P.Wih_d = dWih;  P.Whh_d = dWhh;
    P.oWih_f = WihF_bf; P.oWhh_f = WhhF_bf; P.oWih_b = WihB_bf; P.oWhh_b = WhhB_bf;
    P.oWih_d = WihD_bf; P.oWhh_d = WhhD_bf;
    P.Ws = Ws_w; P.Wh = Wh_w; P.lin = lin_w; P.outw = out_w;
    P.oWs = Ws_bf; P.oWh = Wh_bf; P.olin = lin_bf; P.oout = out_bf;
    P.emb_src = emb_src; P.emb_tgt = emb_tgt; P.source = source; P.target = target;
    P.A_src = A_src; P.A_tgt = A_tgt;
    P.bihf = ebihF; P.bhhf = ebhhF; P.bihb = ebihB; P.bhhb = ebhhB;
    P.bihd = dbih;  P.bhhd = dbhh;
    P.bsumf = bsumF; P.bsumb = bsumB; P.bsumd = bsumD;
    P.tgtf = tgtf;
    P.hF0 = hF_sl; P.hB0 = hB_sl;
    P.dout = outp; P.bar = bar;
    prep_kernel<<<dim3(2048), 256, 0, stream>>>(P);

    // pre-GEMMs: x@Wih^T + (bih+bhh), all timesteps batched
    gemm128<4><<<dim3(16, 32), 256, 0, stream>>>(A_src, 512, WihF_bf, 512, 512,
        bsumF, preF, 2048, nullptr, 0);
    gemm128<4><<<dim3(16, 32), 256, 0, stream>>>(A_src, 512, WihB_bf, 512, 512,
        bsumB, preB, 2048, nullptr, 0);
    gemm128<4><<<dim3(16, 25), 256, 0, stream>>>(A_tgt, 512, WihD_bf, 512, 512,
        bsumD, preD, 2048, nullptr, 0);

    // persistent bi-encoder (64 steps, one launch)
    EncDir F, Bd;
    F.Whh = WhhF_bf; F.pre = preF; F.hslots = hF_sl; F.hs = hsF; F.cfin = cFf;
    Bd.Whh = WhhB_bf; Bd.pre = preB; Bd.hslots = hB_sl; Bd.hs = hsB; Bd.cfin = cBf;
    enc_kernel<<<dim3(64), 256, 0, stream>>>(F, Bd, bar);

    mid_kernel<<<dim3(1024), 256, 0, stream>>>(hsF, hsB, cFf, cBf,
        enc_out, encout_bf, hxbuf, cdec0);

    // enc_feat = enc_out @ Wh^T + Wh_b
    gemm128<0><<<dim3(4, 32), 256, 0, stream>>>(encout_bf, 512, Wh_bf, 512, 512,
        Wh_b, enc_feat, 512, nullptr, 0);

    // persistent decoder (50 steps, one launch)
    dec_kernel<<<dim3(32), 256, 0, stream>>>(WhhD_bf, preD, hxbuf, cdec0,
        cat_bf, bar + 1);

    // batched heads
    gemm128<0><<<dim3(4, 25), 256, 0, stream>>>(hxbuf + 32768, 512, Ws_bf, 512, 512,
        Ws_b, decf, 512, nullptr, 0);
    attn_scores<<<dim3(50, 64), 256, 0, stream>>>(enc_feat, decf, v_w, v_b, attn);
    softmax_mask<<<dim3(800), 256, 0, stream>>>(attn, source);
    content_cat<<<dim3(50, 64), 256, 0, stream>>>(attn, enc_out, cat_bf);
    gemm128<1><<<dim3(4, 25), 256, 0, stream>>>(cat_bf, 1024, lin_bf, 1024, 1024,
        lin_b, hxnew, 512, nullptr, 0);
    gemm128<3><<<dim3(250, 25), 256, 0, stream>>>(hxnew, 512, out_bf, 512, 512,
        out_b, nullptr, 0, partial, 500);
    loss_kernel<<<dim3(50), 256, 0, stream>>>(partial, hxnew, out_bf, out_b,
        tgtf, outp);
}

// Round 8
// 1356.660 us; speedup vs baseline: 2.2996x; 1.1260x over previous
//
#include <hip/hip_runtime.h>

// ---------------------------------------------------------------------------
// EncoderDecoder (bi-LSTM encoder + attention decoder + CE loss), MI355X.
// R6 profile: enc_kernel 558us (8.7us/step), MfmaUtil 1.2% -> barrier-bound;
// __threadfence() pair = buffer_wbl2 + buffer_inv per step (L2 flush).
// R8: fully symmetric fence-free exchange. h-state is written with agent-scope
// RELAXED atomic stores AND read with agent-scope RELAXED atomic loads (u64),
// so both sides meet at the coherence point (L3) -- no buffer_wbl2/buffer_inv,
// no reliance on L2 state at all for the exchanged data. Barrier = vmcnt(0)
// drain + relaxed atomicAdd + relaxed agent spin (spin HW-verified in R6).
// pre/Whh stay L2-cached across steps. Split counters per direction; final
// barrier skipped. Plain cross-kernel reads of h slots (mid, dec_f GEMM) are
// safe: slot values are bit-identical across graph replays (deterministic),
// and the first call has no cached copies.
// ---------------------------------------------------------------------------

#define DI __device__ __forceinline__

typedef __attribute__((ext_vector_type(8))) short bf16x8;
typedef __attribute__((ext_vector_type(4))) float f32x4;
typedef const __attribute__((address_space(1))) void* gp1_t;
typedef __attribute__((address_space(3))) void* lp3_t;

DI float bf2f(short u) {
    union { float f; unsigned u; } c; c.u = ((unsigned)(unsigned short)u) << 16; return c.f;
}
DI short f2bf(float f) {
    union { float f; unsigned u; } c; c.f = f;
    unsigned r = c.u + 0x7fffu + ((c.u >> 16) & 1u);
    return (short)(r >> 16);
}
DI float sigm(float x) { return 1.f / (1.f + __expf(-x)); }
DI float tanh_(float x) {
    float e = __expf(-2.f * fabsf(x));
    float r = (1.f - e) / (1.f + e);
    return copysignf(r, x);
}

// ---------------------------------------------------------------------------
// m97-structure GEMM: C[m][n] = sum_k A[m][k]*B[n][k], row-major, K contig.
// 128x128 tile, BK=64, 4 waves, 4x4 16x16x32 frags, global_load_lds(16B),
// XOR slot swizzle. EPI 0: f32 v+bias. EPI 1: bf16 tanh(v+bias).
// EPI 4: bf16 v+bias. EPI 3: partial sumexp per (row, bx*2+wc).
// ---------------------------------------------------------------------------
template<int EPI>
__global__ __launch_bounds__(256) void gemm128(
    const short* __restrict__ A, int lda,
    const short* __restrict__ B, int ldb,
    int K,
    const float* __restrict__ bias,
    void* __restrict__ Cout, int ldc,
    float* __restrict__ partial, int pstride)
{
    __shared__ short lA[8192], lB[8192];
    const int tid = threadIdx.x;
    const int lane = tid & 63, wave = tid >> 6;
    const int wr = wave >> 1, wc = wave & 1;
    const int mbase = blockIdx.y * 128, nbase = blockIdx.x * 128;

    const char* ga[4]; const char* gb[4];
    {
        int r = tid >> 3, sl = tid & 7;
#pragma unroll
        for (int R = 0; R < 4; ++R) {
            int row = R * 32 + r;
            int so = (sl ^ (row & 7)) << 4;
            ga[R] = (const char*)(A + (size_t)(mbase + row) * lda) + so;
            gb[R] = (const char*)(B + (size_t)(nbase + row) * ldb) + so;
        }
    }
    const int r7 = lane & 7, gq = lane >> 4;
    int abase[4], bbase[4];
#pragma unroll
    for (int i = 0; i < 4; ++i) {
        abase[i] = (wr * 64 + i * 16 + (lane & 15)) * 128;
        bbase[i] = (wc * 64 + i * 16 + (lane & 15)) * 128;
    }
    int sloff[2];
#pragma unroll
    for (int h = 0; h < 2; ++h) sloff[h] = ((h * 4 + gq) ^ r7) << 4;

    f32x4 acc[4][4];
#pragma unroll
    for (int i = 0; i < 4; ++i)
#pragma unroll
        for (int j = 0; j < 4; ++j) acc[i][j] = (f32x4){0.f, 0.f, 0.f, 0.f};

    for (int kk = 0; kk < K; kk += 64) {
#pragma unroll
        for (int R = 0; R < 4; ++R)
            __builtin_amdgcn_global_load_lds((gp1_t)ga[R],
                (lp3_t)((char*)lA + R * 4096 + tid * 16), 16, 0, 0);
#pragma unroll
        for (int R = 0; R < 4; ++R)
            __builtin_amdgcn_global_load_lds((gp1_t)gb[R],
                (lp3_t)((char*)lB + R * 4096 + tid * 16), 16, 0, 0);
#pragma unroll
        for (int R = 0; R < 4; ++R) { ga[R] += 128; gb[R] += 128; }
        __syncthreads();
#pragma unroll
        for (int h = 0; h < 2; ++h) {
            bf16x8 af[4], bfv[4];
#pragma unroll
            for (int i = 0; i < 4; ++i)
                af[i] = *(const bf16x8*)((const char*)lA + abase[i] + sloff[h]);
#pragma unroll
            for (int j = 0; j < 4; ++j)
                bfv[j] = *(const bf16x8*)((const char*)lB + bbase[j] + sloff[h]);
#pragma unroll
            for (int i = 0; i < 4; ++i)
#pragma unroll
                for (int j = 0; j < 4; ++j)
                    acc[i][j] = __builtin_amdgcn_mfma_f32_16x16x32_bf16(
                        af[i], bfv[j], acc[i][j], 0, 0, 0);
        }
        __syncthreads();
    }

    float bv[4];
#pragma unroll
    for (int j = 0; j < 4; ++j) bv[j] = bias[nbase + wc * 64 + j * 16 + (lane & 15)];

    if constexpr (EPI == 3) {
#pragma unroll
        for (int i = 0; i < 4; ++i)
#pragma unroll
            for (int r = 0; r < 4; ++r) {
                float es = 0.f;
#pragma unroll
                for (int j = 0; j < 4; ++j) es += __expf(acc[i][j][r] + bv[j]);
                es += __shfl_xor(es, 1); es += __shfl_xor(es, 2);
                es += __shfl_xor(es, 4); es += __shfl_xor(es, 8);
                if ((lane & 15) == 0) {
                    int row = mbase + wr * 64 + i * 16 + (lane >> 4) * 4 + r;
                    partial[(size_t)row * pstride + blockIdx.x * 2 + wc] = es;
                }
            }
    } else {
#pragma unroll
        for (int i = 0; i < 4; ++i)
#pragma unroll
            for (int j = 0; j < 4; ++j)
#pragma unroll
                for (int r = 0; r < 4; ++r) {
                    int row = mbase + wr * 64 + i * 16 + (lane >> 4) * 4 + r;
                    int col = nbase + wc * 64 + j * 16 + (lane & 15);
                    float v = acc[i][j][r] + bv[j];
                    if constexpr (EPI == 0)
                        ((float*)Cout)[(size_t)row * ldc + col] = v;
                    else if constexpr (EPI == 1)
                        ((short*)Cout)[(size_t)row * ldc + col] = f2bf(tanh_(v));
                    else
                        ((short*)Cout)[(size_t)row * ldc + col] = f2bf(v);
                }
    }
}

// ---------------------------------------------------------------------------
// Fence-free grid barrier: vmcnt(0) drains the agent-scope h stores (already
// routed to L3), then relaxed agent add + spin. No cache maintenance.
// ---------------------------------------------------------------------------
DI void gbarf(int* bar, int target)
{
    asm volatile("s_waitcnt vmcnt(0)" ::: "memory");
    __syncthreads();
    if (threadIdx.x == 0) {
        atomicAdd(bar, 1);
        while (__hip_atomic_load(bar, __ATOMIC_RELAXED, __HIP_MEMORY_SCOPE_AGENT) < target)
            __builtin_amdgcn_s_sleep(2);
    }
    __syncthreads();
}

DI void store_h2(short* p, float h0, float h1)
{
    unsigned v = ((unsigned)(unsigned short)f2bf(h0)) |
                 (((unsigned)(unsigned short)f2bf(h1)) << 16);
    __hip_atomic_store((unsigned*)p, v, __ATOMIC_RELAXED, __HIP_MEMORY_SCOPE_AGENT);
}

// Stage one 64x512 bf16 h slot into LDS (swizzled) with agent-scope coherent
// loads -- reads meet the producer's agent stores at L3, independent of any
// stale L2/L1 state. 32 x u64 per thread; all indices compile-time (rule #20).
DI void stage_h_coherent(const char* hsrc, char* hl, int tid, int swave, int ssl)
{
    unsigned long long tv[32];
#pragma unroll
    for (int R = 0; R < 16; ++R) {
        int row = R * 4 + swave;
        const unsigned long long* sp = (const unsigned long long*)
            (hsrc + row * 1024 + ((ssl ^ (row & 7)) << 4));
        tv[2 * R]     = __hip_atomic_load(sp,     __ATOMIC_RELAXED, __HIP_MEMORY_SCOPE_AGENT);
        tv[2 * R + 1] = __hip_atomic_load(sp + 1, __ATOMIC_RELAXED, __HIP_MEMORY_SCOPE_AGENT);
    }
#pragma unroll
    for (int R = 0; R < 16; ++R) {
        *(unsigned long long*)(hl + R * 4096 + tid * 16)     = tv[2 * R];
        *(unsigned long long*)(hl + R * 4096 + tid * 16 + 8) = tv[2 * R + 1];
    }
}

// ---------------------------------------------------------------------------
// Persistent encoder: 64 blocks (32 fwd + 32 bwd), separate counters.
// Block owns 64 gate cols (16 h dims); Whh frags in regs; c in regs;
// h staged to LDS each step via agent-coherent loads.
// ---------------------------------------------------------------------------
struct EncDir {
    const short* Whh;   // permuted 2048x512 bf16
    const short* pre;   // [64 t][64 b][2048] bf16 (bias folded)
    short* hslots;      // 65 slots x (64x512) bf16
    float* cfin;        // 64x512 f32 final cell state
};

__global__ __launch_bounds__(256) void enc_kernel(EncDir F, EncDir Bd, int* bar)
{
    const int isB = (blockIdx.x >= 32) ? 1 : 0;
    const EncDir E = isB ? Bd : F;
    int* mybar = bar + isB;
    const int nb = blockIdx.x & 31;
    const int tid = threadIdx.x, lane = tid & 63, wave = tid >> 6;
    const int lc = wave * 16 + (lane & 15);
    const int ncol = nb * 64 + lc;

    bf16x8 bq[16];
    {
        const short* bp = E.Whh + (size_t)ncol * 512 + ((lane >> 4) * 8);
#pragma unroll
        for (int ks = 0; ks < 16; ++ks) bq[ks] = *(const bf16x8*)(bp + ks * 32);
    }
    float cr[4] = {0.f, 0.f, 0.f, 0.f};

    __shared__ short hl[32768];   // 64KB staged h (swizzled slots)
    __shared__ float g[64 * 65];

    const int swave = tid >> 6, ssl = tid & 63;
    const int r7 = lane & 7, gq = lane >> 4;
    const int hb_base = (lane & 15) << 10;

    for (int s = 0; s < 64; ++s) {
        stage_h_coherent((const char*)E.hslots + (size_t)s * 65536,
                         (char*)hl, tid, swave, ssl);
        __syncthreads();

        f32x4 acc[4];
#pragma unroll
        for (int i = 0; i < 4; ++i) acc[i] = (f32x4){0.f, 0.f, 0.f, 0.f};
#pragma unroll
        for (int ks = 0; ks < 16; ++ks) {
            const char* hb = (const char*)hl + hb_base + (((ks * 4 + gq) ^ r7) << 4);
#pragma unroll
            for (int mt = 0; mt < 4; ++mt)
                acc[mt] = __builtin_amdgcn_mfma_f32_16x16x32_bf16(
                    *(const bf16x8*)(hb + mt * 16384), bq[ks], acc[mt], 0, 0, 0);
        }
#pragma unroll
        for (int mt = 0; mt < 4; ++mt)
#pragma unroll
            for (int r = 0; r < 4; ++r)
                g[(mt * 16 + gq * 4 + r) * 65 + lc] = acc[mt][r];
        __syncthreads();

        const int tf = isB ? (63 - s) : s;
        const short* prr = E.pre + (size_t)tf * 131072;
        short* hw = E.hslots + (size_t)(s + 1) * 32768;
#pragma unroll
        for (int it = 0; it < 2; ++it) {
            int b = (tid >> 3) + 32 * it;
            int jj = 2 * (tid & 7);
            int j = nb * 16 + jj;
            bf16x8 pv = *(const bf16x8*)(prr + b * 2048 + nb * 64 + jj * 4);
            float gi0 = g[b * 65 + jj * 4 + 0] + bf2f(pv[0]);
            float gf0 = g[b * 65 + jj * 4 + 1] + bf2f(pv[1]);
            float gg0 = g[b * 65 + jj * 4 + 2] + bf2f(pv[2]);
            float go0 = g[b * 65 + jj * 4 + 3] + bf2f(pv[3]);
            float gi1 = g[b * 65 + jj * 4 + 4] + bf2f(pv[4]);
            float gf1 = g[b * 65 + jj * 4 + 5] + bf2f(pv[5]);
            float gg1 = g[b * 65 + jj * 4 + 6] + bf2f(pv[6]);
            float go1 = g[b * 65 + jj * 4 + 7] + bf2f(pv[7]);
            float cn0 = sigm(gf0) * cr[it * 2 + 0] + sigm(gi0) * tanh_(gg0);
            float cn1 = sigm(gf1) * cr[it * 2 + 1] + sigm(gi1) * tanh_(gg1);
            float h0 = sigm(go0) * tanh_(cn0);
            float h1 = sigm(go1) * tanh_(cn1);
            cr[it * 2 + 0] = cn0; cr[it * 2 + 1] = cn1;
            store_h2(hw + b * 512 + j, h0, h1);
            if (s == 63) {
                E.cfin[b * 512 + j] = cn0;
                E.cfin[b * 512 + j + 1] = cn1;
            }
        }
        if (s < 63) gbarf(mybar, 32 * (s + 1));
    }
}

// ---------------------------------------------------------------------------
// Persistent decoder: 32 blocks, 50 steps; also writes cat right half.
// ---------------------------------------------------------------------------
__global__ __launch_bounds__(256) void dec_kernel(
    const short* __restrict__ Whh, const short* __restrict__ pre,
    short* __restrict__ hslots, const float* __restrict__ c0,
    short* __restrict__ cat, int* __restrict__ bar)
{
    const int nb = blockIdx.x;
    const int tid = threadIdx.x, lane = tid & 63, wave = tid >> 6;
    const int lc = wave * 16 + (lane & 15);
    const int ncol = nb * 64 + lc;

    bf16x8 bq[16];
    {
        const short* bp = Whh + (size_t)ncol * 512 + ((lane >> 4) * 8);
#pragma unroll
        for (int ks = 0; ks < 16; ++ks) bq[ks] = *(const bf16x8*)(bp + ks * 32);
    }
    float cr[4];
#pragma unroll
    for (int it = 0; it < 2; ++it) {
        int b = (tid >> 3) + 32 * it;
        int j = nb * 16 + 2 * (tid & 7);
        cr[it * 2 + 0] = c0[b * 512 + j];
        cr[it * 2 + 1] = c0[b * 512 + j + 1];
    }

    __shared__ short hl[32768];
    __shared__ float g[64 * 65];
    const int swave = tid >> 6, ssl = tid & 63;
    const int r7 = lane & 7, gq = lane >> 4;
    const int hb_base = (lane & 15) << 10;

    for (int t = 0; t < 50; ++t) {
        stage_h_coherent((const char*)hslots + (size_t)t * 65536,
                         (char*)hl, tid, swave, ssl);
        __syncthreads();

        f32x4 acc[4];
#pragma unroll
        for (int i = 0; i < 4; ++i) acc[i] = (f32x4){0.f, 0.f, 0.f, 0.f};
#pragma unroll
        for (int ks = 0; ks < 16; ++ks) {
            const char* hb = (const char*)hl + hb_base + (((ks * 4 + gq) ^ r7) << 4);
#pragma unroll
            for (int mt = 0; mt < 4; ++mt)
                acc[mt] = __builtin_amdgcn_mfma_f32_16x16x32_bf16(
                    *(const bf16x8*)(hb + mt * 16384), bq[ks], acc[mt], 0, 0, 0);
        }
#pragma unroll
        for (int mt = 0; mt < 4; ++mt)
#pragma unroll
            for (int r = 0; r < 4; ++r)
                g[(mt * 16 + gq * 4 + r) * 65 + lc] = acc[mt][r];
        __syncthreads();

        const short* prr = pre + (size_t)t * 131072;
        short* hw = hslots + (size_t)(t + 1) * 32768;
        short* cw = cat + (size_t)t * 65536 + 512;
#pragma unroll
        for (int it = 0; it < 2; ++it) {
            int b = (tid >> 3) + 32 * it;
            int jj = 2 * (tid & 7);
            int j = nb * 16 + jj;
            bf16x8 pv = *(const bf16x8*)(prr + b * 2048 + nb * 64 + jj * 4);
            float gi0 = g[b * 65 + jj * 4 + 0] + bf2f(pv[0]);
            float gf0 = g[b * 65 + jj * 4 + 1] + bf2f(pv[1]);
            float gg0 = g[b * 65 + jj * 4 + 2] + bf2f(pv[2]);
            float go0 = g[b * 65 + jj * 4 + 3] + bf2f(pv[3]);
            float gi1 = g[b * 65 + jj * 4 + 4] + bf2f(pv[4]);
            float gf1 = g[b * 65 + jj * 4 + 5] + bf2f(pv[5]);
            float gg1 = g[b * 65 + jj * 4 + 6] + bf2f(pv[6]);
            float go1 = g[b * 65 + jj * 4 + 7] + bf2f(pv[7]);
            float cn0 = sigm(gf0) * cr[it * 2 + 0] + sigm(gi0) * tanh_(gg0);
            float cn1 = sigm(gf1) * cr[it * 2 + 1] + sigm(gi1) * tanh_(gg1);
            float h0 = sigm(go0) * tanh_(cn0);
            float h1 = sigm(go1) * tanh_(cn1);
            cr[it * 2 + 0] = cn0; cr[it * 2 + 1] = cn1;
            store_h2(hw + b * 512 + j, h0, h1);
            unsigned cv = ((unsigned)(unsigned short)f2bf(h0)) |
                          (((unsigned)(unsigned short)f2bf(h1)) << 16);
            *(unsigned*)(cw + b * 1024 + j) = cv;   // consumed after kernel end
        }
        if (t < 49) gbarf(bar, 32 * (t + 1));
    }
}

// ---------------------------------------------------------------------------
// prep: weight conversion/permutation, embedding gathers, bias sums, tgt
// indices, zero-init (h slot 0, d_out, 4 barrier counters).
// ---------------------------------------------------------------------------
struct PrepArgs {
    const float *Wih_f, *Whh_f, *Wih_b, *Whh_b, *Wih_d, *Whh_d;
    short *oWih_f, *oWhh_f, *oWih_b, *oWhh_b, *oWih_d, *oWhh_d;
    const float *Ws, *Wh, *lin, *outw;
    short *oWs, *oWh, *olin, *oout;
    const float *emb_src, *emb_tgt;
    const int *source, *target;
    short *A_src, *A_tgt;
    const float *bihf, *bhhf, *bihb, *bhhb, *bihd, *bhhd;
    float *bsumf, *bsumb, *bsumd;
    int *tgtf;
    short *hF0, *hB0;
    float *dout;
    int *bar;           // 4 counters
};

__global__ __launch_bounds__(256) void prep_kernel(PrepArgs P)
{
    const long long total = 6291456LL + 262144 + 262144 + 524288 + 16384000
                          + 2097152 + 1638400 + 6144 + 3200 + 65536 + 5;
    for (long long i = (long long)blockIdx.x * 256 + threadIdx.x; i < total;
         i += (long long)gridDim.x * 256) {
        long long t = i;
        if (t < 6291456LL) {
            int seg = (int)(t >> 20); int r = (int)(t & 1048575);
            int n = r >> 9, k = r & 511;
            int orig = (n & 3) * 512 + (n >> 2);
            const float* s; short* d;
            switch (seg) {
                case 0: s = P.Wih_f; d = P.oWih_f; break;
                case 1: s = P.Whh_f; d = P.oWhh_f; break;
                case 2: s = P.Wih_b; d = P.oWih_b; break;
                case 3: s = P.Whh_b; d = P.oWhh_b; break;
                case 4: s = P.Wih_d; d = P.oWih_d; break;
                default: s = P.Whh_d; d = P.oWhh_d; break;
            }
            d[n * 512 + k] = f2bf(s[orig * 512 + k]);
            continue;
        }
        t -= 6291456LL;
        if (t < 262144) { P.oWs[t] = f2bf(P.Ws[t]); continue; } t -= 262144;
        if (t < 262144) { P.oWh[t] = f2bf(P.Wh[t]); continue; } t -= 262144;
        if (t < 524288) { P.olin[t] = f2bf(P.lin[t]); continue; } t -= 524288;
        if (t < 16384000) { P.oout[t] = f2bf(P.outw[t]); continue; } t -= 16384000;
        if (t < 2097152) {
            int r = (int)(t >> 9), k = (int)(t & 511);
            int tt = r >> 6, b = r & 63;
            int tok = P.source[b * 64 + tt];
            P.A_src[t] = tok ? f2bf(P.emb_src[(size_t)tok * 512 + k]) : (short)0;
            continue;
        } t -= 2097152;
        if (t < 1638400) {
            int r = (int)(t >> 9), k = (int)(t & 511);
            int tt = r >> 6, b = r & 63;
            int tok = P.target[b * 51 + tt];
            P.A_tgt[t] = tok ? f2bf(P.emb_tgt[(size_t)tok * 512 + k]) : (short)0;
            continue;
        } t -= 1638400;
        if (t < 6144) {
            int net = (int)(t >> 11); int n = (int)(t & 2047);
            int orig = (n & 3) * 512 + (n >> 2);
            if (net == 0)      P.bsumf[n] = P.bihf[orig] + P.bhhf[orig];
            else if (net == 1) P.bsumb[n] = P.bihb[orig] + P.bhhb[orig];
            else               P.bsumd[n] = P.bihd[orig] + P.bhhd[orig];
            continue;
        } t -= 6144;
        if (t < 3200) {
            int s = (int)t >> 6, b = (int)t & 63;
            P.tgtf[t] = P.target[b * 51 + s + 1];
            continue;
        } t -= 3200;
        if (t < 65536) {
            if (t < 32768) P.hF0[t] = 0; else P.hB0[t - 32768] = 0;
            continue;
        } t -= 65536;
        if (t == 0) P.dout[0] = 0.f;
        else P.bar[t - 1] = 0;
    }
}

// ---------------------------------------------------------------------------
// mid: enc_out = h_f + h_b from bf16 slots (fp32 + bf16), decoder init state.
// fwd time tt -> slot tt+1; bwd time tt -> slot 64-tt.
// ---------------------------------------------------------------------------
__global__ __launch_bounds__(256) void mid_kernel(
    const short* __restrict__ hFsl, const short* __restrict__ hBsl,
    const float* __restrict__ cFf, const float* __restrict__ cBf,
    float* __restrict__ enc_out, short* __restrict__ enc_out_bf,
    short* __restrict__ hx0, float* __restrict__ cdec0)
{
    const int total = 64 * 64 * 512 + 64 * 512;
    for (int i = blockIdx.x * 256 + threadIdx.x; i < total; i += gridDim.x * 256) {
        if (i < 64 * 64 * 512) {
            int r = i >> 9, d = i & 511;
            int b = r >> 6, tt = r & 63;
            float v = bf2f(hFsl[(size_t)(tt + 1) * 32768 + b * 512 + d])
                    + bf2f(hBsl[(size_t)(64 - tt) * 32768 + b * 512 + d]);
            enc_out[i] = v;
            enc_out_bf[i] = f2bf(v);
        } else {
            int j = i - 64 * 64 * 512;
            int b = j >> 9, d = j & 511;
            float h0 = bf2f(hFsl[(size_t)64 * 32768 + b * 512 + d])
                     + bf2f(hBsl[(size_t)64 * 32768 + b * 512 + d]);
            hx0[b * 512 + d] = f2bf(h0);
            cdec0[b * 512 + d] = cFf[b * 512 + d] + cBf[b * 512 + d];
        }
    }
}

// ---------------------------------------------------------------------------
// scores[t][p][q] = v_b + sum_d tanh(enc_feat[p][q][d] + dec_f[t][p][d])*v_w[d]
// ---------------------------------------------------------------------------
__global__ __launch_bounds__(256) void attn_scores(
    const float* __restrict__ enc_feat, const float* __restrict__ dec_f,
    const float* __restrict__ v_w, const float* __restrict__ v_b,
    float* __restrict__ scores)
{
    int p = blockIdx.y;
    int tp = blockIdx.x * 64 + p;
    __shared__ float df[512], vw[512];
    for (int i = threadIdx.x; i < 512; i += 256) {
        df[i] = dec_f[(size_t)tp * 512 + i];
        vw[i] = v_w[i];
    }
    __syncthreads();
    int lane = threadIdx.x & 63, wave = threadIdx.x >> 6;
    float vb = v_b[0];
    for (int q = wave; q < 64; q += 4) {
        const float* ef = enc_feat + (size_t)(p * 64 + q) * 512;
        float s = 0.f;
        for (int d = lane; d < 512; d += 64)
            s += tanh_(ef[d] + df[d]) * vw[d];
        for (int o = 32; o > 0; o >>= 1) s += __shfl_xor(s, o);
        if (lane == 0) scores[(size_t)tp * 64 + q] = s + vb;
    }
}

__global__ __launch_bounds__(256) void softmax_mask(
    float* __restrict__ attn, const int* __restrict__ source)
{
    int row = blockIdx.x * 4 + (threadIdx.x >> 6);
    int lane = threadIdx.x & 63;
    int p = row & 63;
    float v = attn[(size_t)row * 64 + lane];
    float m = v;
    for (int o = 32; o > 0; o >>= 1) m = fmaxf(m, __shfl_xor(m, o));
    float e = __expf(v - m);
    float s = e;
    for (int o = 32; o > 0; o >>= 1) s += __shfl_xor(s, o);
    float mask = (source[lane * 64 + p] == 0) ? 1.f : 0.f;
    attn[(size_t)row * 64 + lane] = (e / s) * mask;
}

__global__ __launch_bounds__(256) void content_cat(
    const float* __restrict__ attn, const float* __restrict__ enc_out,
    short* __restrict__ cat)
{
    int q = blockIdx.y;
    int tq = blockIdx.x * 64 + q;
    __shared__ float ac[64];
    if (threadIdx.x < 64)
        ac[threadIdx.x] = attn[(size_t)(blockIdx.x * 64 + threadIdx.x) * 64 + q];
    __syncthreads();
    for (int d = threadIdx.x; d < 512; d += 256) {
        float s = 0.f;
#pragma unroll 8
        for (int pp = 0; pp < 64; ++pp)
            s += ac[pp] * enc_out[(size_t)(pp * 64 + q) * 512 + d];
        cat[(size_t)tq * 1024 + d] = f2bf(s);
    }
}

__global__ __launch_bounds__(256) void loss_kernel(
    const float* __restrict__ partial, const short* __restrict__ hxnew,
    const short* __restrict__ outw, const float* __restrict__ outb,
    const int* __restrict__ tgtf, float* __restrict__ out)
{
    int t = blockIdx.x;
    int tid = threadIdx.x;
    int b = tid >> 2, c = tid & 3;
    int row = t * 64 + b;
    float s = 0.f;
    for (int j = c; j < 500; j += 4) s += partial[(size_t)row * 500 + j];
    int w = tgtf[row];
    const short* hp = hxnew + (size_t)row * 512 + c * 128;
    const short* wp = outw + (size_t)w * 512 + c * 128;
    float tl = 0.f;
    for (int k2 = 0; k2 < 128; k2 += 8) {
        bf16x8 hv = *(const bf16x8*)(hp + k2);
        bf16x8 wv = *(const bf16x8*)(wp + k2);
#pragma unroll
        for (int u = 0; u < 8; ++u) tl += bf2f(hv[u]) * bf2f(wv[u]);
    }
    s += __shfl_xor(s, 1); s += __shfl_xor(s, 2);
    tl += __shfl_xor(tl, 1); tl += __shfl_xor(tl, 2);
    __shared__ float ce_s[64], va_s[64];
    if (c == 0) {
        float lse = logf(s);
        float ce = lse - (tl + outb[w]);
        float valid = (w != 0) ? 1.f : 0.f;
        ce_s[b] = ce * valid;
        va_s[b] = valid;
    }
    __syncthreads();
    if (tid < 64) {
        float cv = ce_s[tid], vv = va_s[tid];
        for (int o = 32; o > 0; o >>= 1) { cv += __shfl_xor(cv, o); vv += __shfl_xor(vv, o); }
        if (tid == 0) {
            float sl = (vv > 0.f) ? cv / fmaxf(vv, 1.f) : 0.f;
            atomicAdd(out, sl);
        }
    }
}

// ---------------------------------------------------------------------------
extern "C" void kernel_launch(void* const* d_in, const int* in_sizes, int n_in,
                              void* d_out, int out_size, void* d_ws, size_t ws_size,
                              hipStream_t stream)
{
    (void)in_sizes; (void)n_in; (void)out_size; (void)ws_size;
    const int*   source  = (const int*)  d_in[0];
    const int*   target  = (const int*)  d_in[1];
    const float* emb_src = (const float*)d_in[2];
    const float* emb_tgt = (const float*)d_in[3];
    const float* eWihF   = (const float*)d_in[4];
    const float* eWhhF   = (const float*)d_in[5];
    const float* ebihF   = (const float*)d_in[6];
    const float* ebhhF   = (const float*)d_in[7];
    const float* eWihB   = (const float*)d_in[8];
    const float* eWhhB   = (const float*)d_in[9];
    const float* ebihB   = (const float*)d_in[10];
    const float* ebhhB   = (const float*)d_in[11];
    const float* Wh_w    = (const float*)d_in[12];
    const float* Wh_b    = (const float*)d_in[13];
    const float* dWih    = (const float*)d_in[14];
    const float* dWhh    = (const float*)d_in[15];
    const float* dbih    = (const float*)d_in[16];
    const float* dbhh    = (const float*)d_in[17];
    const float* Ws_w    = (const float*)d_in[18];
    const float* Ws_b    = (const float*)d_in[19];
    const float* v_w     = (const float*)d_in[20];
    const float* v_b     = (const float*)d_in[21];
    const float* lin_w   = (const float*)d_in[22];
    const float* lin_b   = (const float*)d_in[23];
    const float* out_w   = (const float*)d_in[24];
    const float* out_b   = (const float*)d_in[25];

    char* base = (char*)d_ws;
    size_t off = 0;
    auto alloc = [&](size_t bytes) -> char* {
        char* p = base + off;
        off = (off + bytes + 255) & ~(size_t)255;
        return p;
    };
    short* WihF_bf = (short*)alloc(1048576ULL * 2);
    short* WhhF_bf = (short*)alloc(1048576ULL * 2);
    short* WihB_bf = (short*)alloc(1048576ULL * 2);
    short* WhhB_bf = (short*)alloc(1048576ULL * 2);
    short* WihD_bf = (short*)alloc(1048576ULL * 2);
    short* WhhD_bf = (short*)alloc(1048576ULL * 2);
    short* Ws_bf   = (short*)alloc(262144ULL * 2);
    short* Wh_bf   = (short*)alloc(262144ULL * 2);
    short* lin_bf  = (short*)alloc(524288ULL * 2);
    short* out_bf  = (short*)alloc(16384000ULL * 2);
    short* A_src   = (short*)alloc(2097152ULL * 2);
    short* A_tgt   = (short*)alloc(1638400ULL * 2);
    short* preF    = (short*)alloc(8388608ULL * 2);   // dead after encoder
    short* preB    = (short*)alloc(8388608ULL * 2);
    short* preD    = (short*)alloc(6553600ULL * 2);
    short* hF_sl   = (short*)alloc(65ULL * 32768 * 2);
    short* hB_sl   = (short*)alloc(65ULL * 32768 * 2);
    short* hxbuf   = (short*)alloc(51ULL * 32768 * 2);
    short* encout_bf = (short*)alloc(2097152ULL * 2);
    short* cat_bf  = (short*)alloc(3276800ULL * 2);
    short* hxnew   = (short*)alloc(1638400ULL * 2);
    float* bsumF   = (float*)alloc(2048 * 4);
    float* bsumB   = (float*)alloc(2048 * 4);
    float* bsumD   = (float*)alloc(2048 * 4);
    float* cFf     = (float*)alloc(32768ULL * 4);
    float* cBf     = (float*)alloc(32768ULL * 4);
    float* cdec0   = (float*)alloc(32768ULL * 4);
    float* enc_out = (float*)alloc(2097152ULL * 4);
    float* enc_feat= (float*)alloc(2097152ULL * 4);
    float* decf    = (float*)alloc(1638400ULL * 4);
    float* attn    = (float*)alloc(204800ULL * 4);
    int*   tgtf    = (int*)  alloc(3200 * 4);
    int*   bar     = (int*)  alloc(16);          // 4 counters
    float* partial = (float*)preF;               // aliases preF (disjoint lifetime)
    float* outp    = (float*)d_out;

    PrepArgs P;
    P.Wih_f = eWihF; P.Whh_f = eWhhF; P.Wih_b = eWihB; P.Whh_b = eWhhB;
    P.Wih_d = dWih;  P.Whh_d = dWhh;
    P.oWih_f = WihF_bf; P.oWhh_f = WhhF_bf; P.oWih_b = WihB_bf; P.oWhh_b = WhhB_bf;
    P.oWih_d = WihD_bf; P.oWhh_d = WhhD_bf;
    P.Ws = Ws_w; P.Wh = Wh_w; P.lin = lin_w; P.outw = out_w;
    P.oWs = Ws_bf; P.oWh = Wh_bf; P.olin = lin_bf; P.oout = out_bf;
    P.emb_src = emb_src; P.emb_tgt = emb_tgt; P.source = source; P.target = target;
    P.A_src = A_src; P.A_tgt = A_tgt;
    P.bihf = ebihF; P.bhhf = ebhhF; P.bihb = ebihB; P.bhhb = ebhhB;
    P.bihd = dbih;  P.bhhd = dbhh;
    P.bsumf = bsumF; P.bsumb = bsumB; P.bsumd = bsumD;
    P.tgtf = tgtf;
    P.hF0 = hF_sl; P.hB0 = hB_sl;
    P.dout = outp; P.bar = bar;
    prep_kernel<<<dim3(2048), 256, 0, stream>>>(P);

    gemm128<4><<<dim3(16, 32), 256, 0, stream>>>(A_src, 512, WihF_bf, 512, 512,
        bsumF, preF, 2048, nullptr, 0);
    gemm128<4><<<dim3(16, 32), 256, 0, stream>>>(A_src, 512, WihB_bf, 512, 512,
        bsumB, preB, 2048, nullptr, 0);
    gemm128<4><<<dim3(16, 25), 256, 0, stream>>>(A_tgt, 512, WihD_bf, 512, 512,
        bsumD, preD, 2048, nullptr, 0);

    EncDir F, Bd;
    F.Whh = WhhF_bf; F.pre = preF; F.hslots = hF_sl; F.cfin = cFf;
    Bd.Whh = WhhB_bf; Bd.pre = preB; Bd.hslots = hB_sl; Bd.cfin = cBf;
    enc_kernel<<<dim3(64), 256, 0, stream>>>(F, Bd, bar);

    mid_kernel<<<dim3(1024), 256, 0, stream>>>(hF_sl, hB_sl, cFf, cBf,
        enc_out, encout_bf, hxbuf, cdec0);

    gemm128<0><<<dim3(4, 32), 256, 0, stream>>>(encout_bf, 512, Wh_bf, 512, 512,
        Wh_b, enc_feat, 512, nullptr, 0);

    dec_kernel<<<dim3(32), 256, 0, stream>>>(WhhD_bf, preD, hxbuf, cdec0,
        cat_bf, bar + 2);

    gemm128<0><<<dim3(4, 25), 256, 0, stream>>>(hxbuf + 32768, 512, Ws_bf, 512, 512,
        Ws_b, decf, 512, nullptr, 0);
    attn_scores<<<dim3(50, 64), 256, 0, stream>>>(enc_feat, decf, v_w, v_b, attn);
    softmax_mask<<<dim3(800), 256, 0, stream>>>(attn, source);
    content_cat<<<dim3(50, 64), 256, 0, stream>>>(attn, enc_out, cat_bf);
    gemm128<1><<<dim3(4, 25), 256, 0, stream>>>(cat_bf, 1024, lin_bf, 1024, 1024,
        lin_b, hxnew, 512, nullptr, 0);
    gemm128<3><<<dim3(250, 25), 256, 0, stream>>>(hxnew, 512, out_bf, 512, 512,
        out_b, nullptr, 0, partial, 500);
    loss_kernel<<<dim3(50), 256, 0, stream>>>(partial, hxnew, out_bf, out_b,
        tgtf, outp);
}